// Round 1
// baseline (635.195 us; speedup 1.0000x reference)
//
#include <hip/hip_runtime.h>
#include <math.h>

#define CIN 128
#define C4  32
#define HW  12544      // 112*112
#define NPIX 256       // nodes per window
#define KNB 9
#define NWIN 392       // 8 * 7 * 7

__device__ inline double wave_sum(double v) {
#pragma unroll
    for (int off = 32; off; off >>= 1) v += __shfl_down(v, off);
    return v;
}

// ---------------- window pipeline: f-conv + GN + sim/topk + edge MLP ----------------
__global__ __launch_bounds__(256) void win_kernel(
    const float* __restrict__ x_in,
    const float* __restrict__ f_w, const float* __restrict__ f_b,
    const float* __restrict__ f_gn_w, const float* __restrict__ f_gn_b,
    const float* __restrict__ e1_w, const float* __restrict__ e1_b,
    const float* __restrict__ e2_w, const float* __restrict__ e2_b,
    const float* __restrict__ gamma, const float* __restrict__ beta,
    float* __restrict__ gnn)
{
    __shared__ float  wbuf[C4 * CIN];     // f_w transposed [c][o], later e1_w [j][64]
    __shared__ float  xf[NPIX][36];       // padded to 36 for bank spread + 16B align
    __shared__ double invn[NPIX];
    __shared__ double red[8];
    __shared__ float  e1b_s[C4], e2w_s[C4];

    const int win = blockIdx.x;
    const int b   = win / 49;
    const int wg  = (win / 7) % 7;
    const int hg  = win % 7;
    const int t   = threadIdx.x;
    const int py  = t >> 4, px = t & 15;

    // stage f_w transposed: wbuf[c*32 + o] = f_w[o*128 + c]
    for (int i = t; i < C4 * CIN; i += 256) wbuf[(i & 127) * C4 + (i >> 7)] = f_w[i];
    __syncthreads();

    // f = f_w @ x_window + f_b, fp64 accumulation (feeds top-k!)
    const float* xb = x_in + (size_t)b * CIN * HW + (size_t)(wg * 16 + py) * 112 + (hg * 16 + px);
    double acc[C4];
#pragma unroll
    for (int o = 0; o < C4; ++o) acc[o] = 0.0;
    for (int c = 0; c < CIN; ++c) {
        double xv = (double)xb[(size_t)c * HW];
#pragma unroll
        for (int o = 0; o < C4; ++o) acc[o] += (double)wbuf[c * C4 + o] * xv;
    }
    double s1 = 0.0, s2 = 0.0;
#pragma unroll
    for (int o = 0; o < C4; ++o) {
        double v = acc[o] + (double)f_b[o];
        acc[o] = v; s1 += v; s2 += v * v;
    }
    s1 = wave_sum(s1); s2 = wave_sum(s2);
    if ((t & 63) == 0) { red[t >> 6] = s1; red[4 + (t >> 6)] = s2; }
    __syncthreads();
    const double mu   = (red[0] + red[1] + red[2] + red[3]) * (1.0 / 8192.0);
    const double var  = (red[4] + red[5] + red[6] + red[7]) * (1.0 / 8192.0) - mu * mu;
    const double rstd = 1.0 / sqrt(var + 1e-5);

    // xf row (rounded to fp32, used consistently), grid coords, inv norm
    double xad[34];
#pragma unroll
    for (int c = 0; c < C4; ++c) {
        float v = (float)((acc[c] - mu) * rstd * (double)f_gn_w[c] + (double)f_gn_b[c]);
        xf[t][c] = v;
        xad[c] = (double)v;
    }
    const double gstd = sqrt(5440.0 / 255.0) + 1e-5;   // grid std (ddof=1) + eps
    const double ginv = 1.0 / gstd;
    xad[32] = ((double)py - 7.5) * ginv;
    xad[33] = ((double)px - 7.5) * ginv;
    double nrm = 0.0;
#pragma unroll
    for (int c = 0; c < 34; ++c) nrm += xad[c] * xad[c];
    nrm = sqrt(nrm);
    const double inv = 1.0 / fmax(nrm, 1e-8);
    invn[t] = inv;
    __syncthreads();

    // cosine sim row + top-9 (stable insertion: ties keep lowest index, like lax.top_k)
    float tv[KNB]; int ti[KNB];
#pragma unroll
    for (int k = 0; k < KNB; ++k) { tv[k] = -1e30f; ti[k] = 0; }
    for (int m = 0; m < NPIX; ++m) {
        double gy = ((double)(m >> 4) - 7.5) * ginv;
        double gx = ((double)(m & 15) - 7.5) * ginv;
        double d = xad[32] * gy + xad[33] * gx;
#pragma unroll
        for (int c = 0; c < C4; ++c) d += xad[c] * (double)xf[m][c];
        float s = (float)(d * inv * invn[m]);
        if (m != t && s > tv[KNB - 1]) {
            tv[KNB - 1] = s; ti[KNB - 1] = m;
#pragma unroll
            for (int j = KNB - 1; j > 0; --j) {
                if (tv[j] > tv[j - 1]) {
                    float tf = tv[j]; tv[j] = tv[j - 1]; tv[j - 1] = tf;
                    int   tt = ti[j]; ti[j] = ti[j - 1]; ti[j - 1] = tt;
                }
            }
        }
    }
    __syncthreads();

    // edge MLP weights into LDS (reuse wbuf)
    for (int i = t; i < C4 * 2 * C4; i += 256) wbuf[i] = e1_w[i];
    if (t < C4) { e1b_s[t] = e1_b[t]; e2w_s[t] = e2_w[t]; }
    __syncthreads();
    const float e2b = e2_b[0];

    float xfn[C4];
#pragma unroll
    for (int c = 0; c < C4; ++c) xfn[c] = (float)xad[c];
    float outv[C4];
#pragma unroll
    for (int c = 0; c < C4; ++c) outv[c] = 0.f;

    for (int k = 0; k < KNB; ++k) {
        const int m = ti[k];
        float msg[C4];
#pragma unroll
        for (int c = 0; c < C4; ++c) msg[c] = xf[m][c];
        float a2 = 0.f;
        for (int j = 0; j < C4; ++j) {
            float h = e1b_s[j];
#pragma unroll
            for (int d2 = 0; d2 < C4; ++d2) h = fmaf(wbuf[j * 64 + d2], xfn[d2], h);
#pragma unroll
            for (int d2 = 0; d2 < C4; ++d2) h = fmaf(wbuf[j * 64 + 32 + d2], msg[d2], h);
            float sg = 1.f / (1.f + __expf(-h));          // silu = h*sigmoid(h)
            a2 = fmaf(e2w_s[j], h * sg, a2);
        }
        float wgt = 1.f / (1.f + __expf(-(a2 + e2b)));
#pragma unroll
        for (int c = 0; c < C4; ++c) outv[c] = fmaf(wgt, msg[c], outv[c]);
    }

    const float g = gamma[0], be = beta[0];
    float* gp = gnn + (size_t)b * C4 * HW + (size_t)(wg * 16 + py) * 112 + (hg * 16 + px);
#pragma unroll
    for (int c = 0; c < C4; ++c) gp[(size_t)c * HW] = g * outv[c] + be * xfn[c];
}

// ---------------- r-conv stats (sum / sumsq per sample) ----------------
__global__ __launch_bounds__(256) void rstats_kernel(
    const float* __restrict__ x_in,
    const float* __restrict__ r_w, const float* __restrict__ r_b,
    double* __restrict__ stats)
{
    __shared__ float  wt[64 * CIN];   // [c][o'] for current 64-output chunk (32KB)
    __shared__ double red[8];
    const int blk = blockIdx.x;
    const int b   = blk / 49;
    const int t   = threadIdx.x;
    const int p   = (blk % 49) * 256 + t;
    const float* xb = x_in + (size_t)b * CIN * HW + p;

    double s1 = 0.0, s2 = 0.0;
    for (int oc = 0; oc < 2; ++oc) {
        __syncthreads();
        for (int i = t; i < 64 * CIN; i += 256)
            wt[(i & 127) * 64 + (i >> 7)] = r_w[oc * 64 * CIN + i];
        __syncthreads();
        float acc[64];
#pragma unroll
        for (int o = 0; o < 64; ++o) acc[o] = r_b[oc * 64 + o];
        for (int c = 0; c < CIN; ++c) {
            float xv = xb[(size_t)c * HW];
#pragma unroll
            for (int o = 0; o < 64; ++o) acc[o] = fmaf(wt[c * 64 + o], xv, acc[o]);
        }
#pragma unroll
        for (int o = 0; o < 64; ++o) { double v = (double)acc[o]; s1 += v; s2 += v * v; }
    }
    s1 = wave_sum(s1); s2 = wave_sum(s2);
    if ((t & 63) == 0) { red[t >> 6] = s1; red[4 + (t >> 6)] = s2; }
    __syncthreads();
    if (t == 0) {
        atomicAdd(&stats[b * 4 + 0], red[0] + red[1] + red[2] + red[3]);
        atomicAdd(&stats[b * 4 + 1], red[4] + red[5] + red[6] + red[7]);
    }
}

// ---------------- p-conv stats ----------------
__global__ __launch_bounds__(256) void pstats_kernel(
    const float* __restrict__ gnn,
    const float* __restrict__ p_w, const float* __restrict__ p_b,
    double* __restrict__ stats)
{
    __shared__ float  wt[C4 * CIN];   // [c][o], 16KB
    __shared__ double red[8];
    const int blk = blockIdx.x;
    const int b   = blk / 49;
    const int t   = threadIdx.x;
    const int p   = (blk % 49) * 256 + t;
    for (int i = t; i < C4 * CIN; i += 256) wt[(i & 31) * CIN + (i >> 5)] = p_w[i];
    __syncthreads();

    float xv[C4];
    const float* gb = gnn + (size_t)b * C4 * HW + p;
#pragma unroll
    for (int c = 0; c < C4; ++c) xv[c] = gb[(size_t)c * HW];

    double s1 = 0.0, s2 = 0.0;
    for (int oc = 0; oc < 2; ++oc) {
        float acc[64];
#pragma unroll
        for (int o = 0; o < 64; ++o) acc[o] = p_b[oc * 64 + o];
#pragma unroll
        for (int c = 0; c < C4; ++c) {
#pragma unroll
            for (int o = 0; o < 64; ++o) acc[o] = fmaf(wt[c * CIN + oc * 64 + o], xv[c], acc[o]);
        }
#pragma unroll
        for (int o = 0; o < 64; ++o) { double v = (double)acc[o]; s1 += v; s2 += v * v; }
    }
    s1 = wave_sum(s1); s2 = wave_sum(s2);
    if ((t & 63) == 0) { red[t >> 6] = s1; red[4 + (t >> 6)] = s2; }
    __syncthreads();
    if (t == 0) {
        atomicAdd(&stats[b * 4 + 2], red[0] + red[1] + red[2] + red[3]);
        atomicAdd(&stats[b * 4 + 3], red[4] + red[5] + red[6] + red[7]);
    }
}

// ---------------- final: GN(p conv) + GN(r conv) ----------------
__global__ __launch_bounds__(256) void final_kernel(
    const float* __restrict__ x_in, const float* __restrict__ gnn,
    const float* __restrict__ r_w, const float* __restrict__ r_b,
    const float* __restrict__ r_gn_w, const float* __restrict__ r_gn_b,
    const float* __restrict__ p_w, const float* __restrict__ p_b,
    const float* __restrict__ p_gn_w, const float* __restrict__ p_gn_b,
    const double* __restrict__ stats,
    float* __restrict__ out)
{
    __shared__ float rwt[64 * CIN];   // r chunk [c][o'], 32KB (reloaded per chunk)
    __shared__ float pwt[C4 * CIN];   // full p [c][o], 16KB
    const int blk = blockIdx.x;
    const int b   = blk / 49;
    const int t   = threadIdx.x;
    const int p   = (blk % 49) * 256 + t;

    for (int i = t; i < C4 * CIN; i += 256) pwt[(i & 31) * CIN + (i >> 5)] = p_w[i];

    const double NN = (double)CIN * HW;
    const double mu_r = stats[b * 4 + 0] / NN;
    const float  rs_r = (float)(1.0 / sqrt(stats[b * 4 + 1] / NN - mu_r * mu_r + 1e-5));
    const double mu_p = stats[b * 4 + 2] / NN;
    const float  rs_p = (float)(1.0 / sqrt(stats[b * 4 + 3] / NN - mu_p * mu_p + 1e-5));
    const float fmur = (float)mu_r, fmup = (float)mu_p;

    float xg[C4];
    const float* gb = gnn + (size_t)b * C4 * HW + p;
#pragma unroll
    for (int c = 0; c < C4; ++c) xg[c] = gb[(size_t)c * HW];

    const float* xb = x_in + (size_t)b * CIN * HW + p;
    float* ob = out + (size_t)b * CIN * HW + p;

    for (int oc = 0; oc < 2; ++oc) {
        __syncthreads();
        for (int i = t; i < 64 * CIN; i += 256)
            rwt[(i & 127) * 64 + (i >> 7)] = r_w[oc * 64 * CIN + i];
        __syncthreads();
        float accR[64], accP[64];
#pragma unroll
        for (int o = 0; o < 64; ++o) { accR[o] = r_b[oc * 64 + o]; accP[o] = p_b[oc * 64 + o]; }
        for (int c = 0; c < CIN; ++c) {
            float xv = xb[(size_t)c * HW];
#pragma unroll
            for (int o = 0; o < 64; ++o) accR[o] = fmaf(rwt[c * 64 + o], xv, accR[o]);
        }
#pragma unroll
        for (int c = 0; c < C4; ++c) {
#pragma unroll
            for (int o = 0; o < 64; ++o) accP[o] = fmaf(pwt[c * CIN + oc * 64 + o], xg[c], accP[o]);
        }
#pragma unroll
        for (int o = 0; o < 64; ++o) {
            int O = oc * 64 + o;
            float yr = (accR[o] - fmur) * rs_r * r_gn_w[O] + r_gn_b[O];
            float yp = (accP[o] - fmup) * rs_p * p_gn_w[O] + p_gn_b[O];
            ob[(size_t)O * HW] = yp + yr;
        }
    }
}

extern "C" void kernel_launch(void* const* d_in, const int* in_sizes, int n_in,
                              void* d_out, int out_size, void* d_ws, size_t ws_size,
                              hipStream_t stream)
{
    const float* x_in   = (const float*)d_in[0];
    const float* f_w    = (const float*)d_in[1];
    const float* f_b    = (const float*)d_in[2];
    const float* f_gn_w = (const float*)d_in[3];
    const float* f_gn_b = (const float*)d_in[4];
    const float* p_w    = (const float*)d_in[5];
    const float* p_b    = (const float*)d_in[6];
    const float* p_gn_w = (const float*)d_in[7];
    const float* p_gn_b = (const float*)d_in[8];
    const float* r_w    = (const float*)d_in[9];
    const float* r_b    = (const float*)d_in[10];
    const float* r_gn_w = (const float*)d_in[11];
    const float* r_gn_b = (const float*)d_in[12];
    const float* e1_w   = (const float*)d_in[13];
    const float* e1_b   = (const float*)d_in[14];
    const float* e2_w   = (const float*)d_in[15];
    const float* e2_b   = (const float*)d_in[16];
    const float* gamma  = (const float*)d_in[17];
    const float* beta   = (const float*)d_in[18];

    float*  gnn   = (float*)d_ws;
    double* stats = (double*)((char*)d_ws + (size_t)8 * C4 * HW * sizeof(float));

    hipMemsetAsync(stats, 0, 32 * sizeof(double), stream);
    win_kernel<<<NWIN, 256, 0, stream>>>(x_in, f_w, f_b, f_gn_w, f_gn_b,
                                         e1_w, e1_b, e2_w, e2_b, gamma, beta, gnn);
    rstats_kernel<<<NWIN, 256, 0, stream>>>(x_in, r_w, r_b, stats);
    pstats_kernel<<<NWIN, 256, 0, stream>>>(gnn, p_w, p_b, stats);
    final_kernel<<<NWIN, 256, 0, stream>>>(x_in, gnn, r_w, r_b, r_gn_w, r_gn_b,
                                           p_w, p_b, p_gn_w, p_gn_b, stats, (float*)d_out);
}

// Round 2
// 514.974 us; speedup vs baseline: 1.2335x; 1.2335x over previous
//
#include <hip/hip_runtime.h>
#include <math.h>

#define CIN 128
#define C4  32
#define HW  12544      // 112*112
#define NPIX 256       // nodes per window
#define KNB 9
#define NWIN 392       // 8 * 7 * 7

__device__ inline double wave_sum(double v) {
#pragma unroll
    for (int off = 32; off; off >>= 1) v += __shfl_down(v, off);
    return v;
}

// ---------------- window pipeline: f-conv + GN + sim/topk + edge MLP ----------------
// LDS layout (47424 B total, 3 blocks/CU):
//   [0,36864)      xf[256][36] float   (rows 144B, 16B aligned; slots 32/33 grid, 34/35 zero)
//   [0,32768)      wbufd[128][32] double  -- phase-1 only, overlaps xf
//   [36864,45056)  e1w[2048] float
//   [45056,47104)  invn[256] double
//   [47104,47232)  e1b[32];  [47232,47360) e2w[32];  [47360,47424) red[8] double
__global__ __launch_bounds__(256, 2) void win_kernel(
    const float* __restrict__ x_in,
    const float* __restrict__ f_w, const float* __restrict__ f_b,
    const float* __restrict__ f_gn_w, const float* __restrict__ f_gn_b,
    const float* __restrict__ e1_w, const float* __restrict__ e1_b,
    const float* __restrict__ e2_w, const float* __restrict__ e2_b,
    const float* __restrict__ gamma, const float* __restrict__ beta,
    float* __restrict__ gnn)
{
    __shared__ __align__(16) char smem[47424];
    float  (*xf)[36] = (float(*)[36])smem;
    double* wbufd  = (double*)smem;
    float*  e1w    = (float*)(smem + 36864);
    double* invn   = (double*)(smem + 45056);
    float*  e1b_s  = (float*)(smem + 47104);
    float*  e2w_s  = (float*)(smem + 47232);
    double* red    = (double*)(smem + 47360);

    const int win = blockIdx.x;
    const int b   = win / 49;
    const int wg  = (win / 7) % 7;
    const int hg  = win % 7;
    const int t   = threadIdx.x;
    const int py  = t >> 4, px = t & 15;

    // stage f_w transposed as double: wbufd[c*32+o] = f_w[o*128+c]; e1 weights up-front
    for (int i = t; i < C4 * CIN; i += 256) wbufd[(i & 127) * C4 + (i >> 7)] = (double)f_w[i];
    for (int i = t; i < 2048; i += 256) e1w[i] = e1_w[i];
    if (t < C4) { e1b_s[t] = e1_b[t]; e2w_s[t] = e2_w[t]; }
    __syncthreads();

    // f = f_w @ x_window + f_b, fp64 accumulation (feeds top-k!)
    const float* xb = x_in + (size_t)b * CIN * HW + (size_t)(wg * 16 + py) * 112 + (hg * 16 + px);
    double acc[C4];
#pragma unroll
    for (int o = 0; o < C4; ++o) acc[o] = 0.0;
#pragma unroll 4
    for (int c = 0; c < CIN; ++c) {
        double xv = (double)xb[(size_t)c * HW];
#pragma unroll
        for (int o = 0; o < C4; ++o) acc[o] = fma(wbufd[c * C4 + o], xv, acc[o]);
    }
    double s1 = 0.0, s2 = 0.0;
#pragma unroll
    for (int o = 0; o < C4; ++o) {
        double v = acc[o] + (double)f_b[o];
        acc[o] = v; s1 += v; s2 += v * v;
    }
    s1 = wave_sum(s1); s2 = wave_sum(s2);
    if ((t & 63) == 0) { red[t >> 6] = s1; red[4 + (t >> 6)] = s2; }
    __syncthreads();   // also fences wbufd reads before xf overwrites below
    const double mu   = (red[0] + red[1] + red[2] + red[3]) * (1.0 / 8192.0);
    const double var  = (red[4] + red[5] + red[6] + red[7]) * (1.0 / 8192.0) - mu * mu;
    const double rstd = 1.0 / sqrt(var + 1e-5);

    // xf row (rounded to fp32, used consistently), grid coords, inv norm
    double xad[36];
#pragma unroll
    for (int c = 0; c < C4; ++c) {
        float v = (float)((acc[c] - mu) * rstd * (double)f_gn_w[c] + (double)f_gn_b[c]);
        xf[t][c] = v;
        xad[c] = (double)v;
    }
    const double ginv = 1.0 / (sqrt(5440.0 / 255.0) + 1e-5);   // 1/(grid std ddof=1 + eps)
    const float gyf = (float)(((double)py - 7.5) * ginv);
    const float gxf = (float)(((double)px - 7.5) * ginv);
    xf[t][32] = gyf; xf[t][33] = gxf; xf[t][34] = 0.f; xf[t][35] = 0.f;
    xad[32] = (double)gyf; xad[33] = (double)gxf; xad[34] = 0.0; xad[35] = 0.0;
    double nrm = 0.0;
#pragma unroll
    for (int c = 0; c < 34; ++c) nrm += xad[c] * xad[c];
    const double inv = 1.0 / fmax(sqrt(nrm), 1e-8);
    invn[t] = inv;
    __syncthreads();

    // cosine sim row + top-9: 4 independent fp64 chains + branchless stable insert
    const double inv_self = inv;
    float tv[KNB]; int ti[KNB];
#pragma unroll
    for (int k = 0; k < KNB; ++k) { tv[k] = -INFINITY; ti[k] = 0; }
#pragma unroll 2
    for (int m = 0; m < NPIX; ++m) {
        const float4* xm = (const float4*)xf[m];
        double d0 = 0.0, d1 = 0.0, d2 = 0.0, d3 = 0.0;
#pragma unroll
        for (int q = 0; q < 9; ++q) {
            float4 f = xm[q];
            d0 = fma((double)f.x, xad[q * 4 + 0], d0);
            d1 = fma((double)f.y, xad[q * 4 + 1], d1);
            d2 = fma((double)f.z, xad[q * 4 + 2], d2);
            d3 = fma((double)f.w, xad[q * 4 + 3], d3);
        }
        double d = (d0 + d1) + (d2 + d3);
        float s = (float)(d * (inv_self * invn[m]));
        s = (m == t) ? -INFINITY : s;
        // predicated insert: strict '>' keeps earlier (lower m) on ties == lax.top_k
#pragma unroll
        for (int j = KNB - 1; j >= 1; --j) {
            bool cj  = s > tv[j];
            bool cjm = s > tv[j - 1];
            tv[j] = cj ? (cjm ? tv[j - 1] : s) : tv[j];
            ti[j] = cj ? (cjm ? ti[j - 1] : m) : ti[j];
        }
        bool c0 = s > tv[0];
        tv[0] = c0 ? s : tv[0];
        ti[0] = c0 ? m : ti[0];
    }

    // edge MLP: hoist src-half (same for all 9 neighbors)
    float xfn[C4];
#pragma unroll
    for (int c = 0; c < C4; ++c) xfn[c] = (float)xad[c];
    float hs[C4];
#pragma unroll 2
    for (int j = 0; j < C4; ++j) {
        const float4* er = (const float4*)(e1w + j * 64);
        float h0 = e1b_s[j], h1 = 0.f;
#pragma unroll
        for (int q = 0; q < 8; ++q) {
            float4 f = er[q];
            h0 = fmaf(f.x, xfn[q * 4 + 0], h0);
            h1 = fmaf(f.y, xfn[q * 4 + 1], h1);
            h0 = fmaf(f.z, xfn[q * 4 + 2], h0);
            h1 = fmaf(f.w, xfn[q * 4 + 3], h1);
        }
        hs[j] = h0 + h1;
    }
    const float e2b = e2_b[0];
    float wk[KNB];
    for (int k = 0; k < KNB; ++k) {
        const int mm = ti[k];
        float msg[C4];
        const float4* xm = (const float4*)xf[mm];
#pragma unroll
        for (int q = 0; q < 8; ++q) {
            float4 f = xm[q];
            msg[q * 4 + 0] = f.x; msg[q * 4 + 1] = f.y;
            msg[q * 4 + 2] = f.z; msg[q * 4 + 3] = f.w;
        }
        float a2 = 0.f;
#pragma unroll 2
        for (int j = 0; j < C4; ++j) {
            const float4* er = (const float4*)(e1w + j * 64 + 32);
            float h0 = hs[j], h1 = 0.f;
#pragma unroll
            for (int q = 0; q < 8; ++q) {
                float4 f = er[q];
                h0 = fmaf(f.x, msg[q * 4 + 0], h0);
                h1 = fmaf(f.y, msg[q * 4 + 1], h1);
                h0 = fmaf(f.z, msg[q * 4 + 2], h0);
                h1 = fmaf(f.w, msg[q * 4 + 3], h1);
            }
            float h = h0 + h1;
            float sg = 1.f / (1.f + __expf(-h));      // silu = h*sigmoid(h)
            a2 = fmaf(e2w_s[j], h * sg, a2);
        }
        wk[k] = 1.f / (1.f + __expf(-(a2 + e2b)));
    }

    const float g = gamma[0], be = beta[0];
    float* gp = gnn + (size_t)b * C4 * HW + (size_t)(wg * 16 + py) * 112 + (hg * 16 + px);
#pragma unroll
    for (int q = 0; q < 8; ++q) {
        float4 o = {0.f, 0.f, 0.f, 0.f};
#pragma unroll
        for (int k = 0; k < KNB; ++k) {
            float4 f = ((const float4*)xf[ti[k]])[q];
            o.x = fmaf(wk[k], f.x, o.x);
            o.y = fmaf(wk[k], f.y, o.y);
            o.z = fmaf(wk[k], f.z, o.z);
            o.w = fmaf(wk[k], f.w, o.w);
        }
        gp[(size_t)(q * 4 + 0) * HW] = fmaf(g, o.x, be * xfn[q * 4 + 0]);
        gp[(size_t)(q * 4 + 1) * HW] = fmaf(g, o.y, be * xfn[q * 4 + 1]);
        gp[(size_t)(q * 4 + 2) * HW] = fmaf(g, o.z, be * xfn[q * 4 + 2]);
        gp[(size_t)(q * 4 + 3) * HW] = fmaf(g, o.w, be * xfn[q * 4 + 3]);
    }
}

// ---------------- merged conv stats: blocks [0,784) r-conv, [784,1568) p-conv ----------------
__global__ __launch_bounds__(256, 2) void stats_kernel(
    const float* __restrict__ x_in,
    const float* __restrict__ r_w, const float* __restrict__ r_b,
    const float* __restrict__ gnn,
    const float* __restrict__ p_w, const float* __restrict__ p_b,
    double* __restrict__ stats)
{
    __shared__ float  wt[64 * CIN];   // [c][o'] 32KB (r); p uses first 8KB
    __shared__ double red[8];
    const int idx = blockIdx.x;
    const int t   = threadIdx.x;
    double s1 = 0.0, s2 = 0.0;
    int sslot;

    if (idx < 784) {
        const int b = idx / 98, rem = idx % 98;
        const int oc = rem / 49, pg = rem % 49;
        for (int i = t; i < 64 * CIN; i += 256)
            wt[(i & 127) * 64 + (i >> 7)] = r_w[oc * 64 * CIN + i];
        __syncthreads();
        const float* xb = x_in + (size_t)b * CIN * HW + pg * 256 + t;
        float acc[64];
#pragma unroll
        for (int o = 0; o < 64; ++o) acc[o] = r_b[oc * 64 + o];
        for (int c0 = 0; c0 < CIN; c0 += 8) {
            float xv[8];
#pragma unroll
            for (int u = 0; u < 8; ++u) xv[u] = xb[(size_t)(c0 + u) * HW];
#pragma unroll
            for (int u = 0; u < 8; ++u)
#pragma unroll
                for (int o = 0; o < 64; ++o) acc[o] = fmaf(wt[(c0 + u) * 64 + o], xv[u], acc[o]);
        }
#pragma unroll
        for (int o = 0; o < 64; ++o) { double v = (double)acc[o]; s1 += v; s2 += v * v; }
        sslot = b * 4;
    } else {
        const int i2 = idx - 784;
        const int b = i2 / 98, rem = i2 % 98;
        const int oc = rem / 49, pg = rem % 49;
        for (int i = t; i < 64 * C4; i += 256)
            wt[(i & 31) * 64 + (i >> 5)] = p_w[oc * 64 * C4 + i];
        __syncthreads();
        const float* gb = gnn + (size_t)b * C4 * HW + pg * 256 + t;
        float xg[C4];
#pragma unroll
        for (int c = 0; c < C4; ++c) xg[c] = gb[(size_t)c * HW];
        float acc[64];
#pragma unroll
        for (int o = 0; o < 64; ++o) acc[o] = p_b[oc * 64 + o];
#pragma unroll
        for (int c = 0; c < C4; ++c)
#pragma unroll
            for (int o = 0; o < 64; ++o) acc[o] = fmaf(wt[c * 64 + o], xg[c], acc[o]);
#pragma unroll
        for (int o = 0; o < 64; ++o) { double v = (double)acc[o]; s1 += v; s2 += v * v; }
        sslot = b * 4 + 2;
    }
    s1 = wave_sum(s1); s2 = wave_sum(s2);
    if ((t & 63) == 0) { red[t >> 6] = s1; red[4 + (t >> 6)] = s2; }
    __syncthreads();
    if (t == 0) {
        atomicAdd(&stats[sslot + 0], red[0] + red[1] + red[2] + red[3]);
        atomicAdd(&stats[sslot + 1], red[4] + red[5] + red[6] + red[7]);
    }
}

// ---------------- final: GN(r conv) + GN(p conv) + add, split by 64-out chunk ----------------
__global__ __launch_bounds__(256, 2) void final_kernel(
    const float* __restrict__ x_in, const float* __restrict__ gnn,
    const float* __restrict__ r_w, const float* __restrict__ r_b,
    const float* __restrict__ r_gn_w, const float* __restrict__ r_gn_b,
    const float* __restrict__ p_w, const float* __restrict__ p_b,
    const float* __restrict__ p_gn_w, const float* __restrict__ p_gn_b,
    const double* __restrict__ stats,
    float* __restrict__ out)
{
    __shared__ float rwt[64 * CIN];   // 32KB [c][o']
    __shared__ float pwt[64 * C4];    // 8KB  [c][o']
    const int idx = blockIdx.x;
    const int b = idx / 98, rem = idx % 98;
    const int oc = rem / 49, pg = rem % 49;
    const int t = threadIdx.x;

    for (int i = t; i < 64 * CIN; i += 256)
        rwt[(i & 127) * 64 + (i >> 7)] = r_w[oc * 64 * CIN + i];
    for (int i = t; i < 64 * C4; i += 256)
        pwt[(i & 31) * 64 + (i >> 5)] = p_w[oc * 64 * C4 + i];
    __syncthreads();

    const double NN = (double)CIN * HW;
    const double mu_r = stats[b * 4 + 0] / NN;
    const float  rs_r = (float)(1.0 / sqrt(stats[b * 4 + 1] / NN - mu_r * mu_r + 1e-5));
    const double mu_p = stats[b * 4 + 2] / NN;
    const float  rs_p = (float)(1.0 / sqrt(stats[b * 4 + 3] / NN - mu_p * mu_p + 1e-5));
    const float fmur = (float)mu_r, fmup = (float)mu_p;

    const int p = pg * 256 + t;
    const float* xb = x_in + (size_t)b * CIN * HW + p;
    const float* gb = gnn + (size_t)b * C4 * HW + p;
    float* ob = out + (size_t)b * CIN * HW + p;

    float xg[C4];
#pragma unroll
    for (int c = 0; c < C4; ++c) xg[c] = gb[(size_t)c * HW];

    float accR[64], accP[64];
#pragma unroll
    for (int o = 0; o < 64; ++o) { accR[o] = r_b[oc * 64 + o]; accP[o] = p_b[oc * 64 + o]; }
    for (int c0 = 0; c0 < CIN; c0 += 8) {
        float xv[8];
#pragma unroll
        for (int u = 0; u < 8; ++u) xv[u] = xb[(size_t)(c0 + u) * HW];
#pragma unroll
        for (int u = 0; u < 8; ++u)
#pragma unroll
            for (int o = 0; o < 64; ++o) accR[o] = fmaf(rwt[(c0 + u) * 64 + o], xv[u], accR[o]);
    }
#pragma unroll
    for (int c = 0; c < C4; ++c)
#pragma unroll
        for (int o = 0; o < 64; ++o) accP[o] = fmaf(pwt[c * 64 + o], xg[c], accP[o]);

#pragma unroll
    for (int o = 0; o < 64; ++o) {
        const int O = oc * 64 + o;
        float yr = (accR[o] - fmur) * rs_r * r_gn_w[O] + r_gn_b[O];
        float yp = (accP[o] - fmup) * rs_p * p_gn_w[O] + p_gn_b[O];
        ob[(size_t)O * HW] = yp + yr;
    }
}

extern "C" void kernel_launch(void* const* d_in, const int* in_sizes, int n_in,
                              void* d_out, int out_size, void* d_ws, size_t ws_size,
                              hipStream_t stream)
{
    const float* x_in   = (const float*)d_in[0];
    const float* f_w    = (const float*)d_in[1];
    const float* f_b    = (const float*)d_in[2];
    const float* f_gn_w = (const float*)d_in[3];
    const float* f_gn_b = (const float*)d_in[4];
    const float* p_w    = (const float*)d_in[5];
    const float* p_b    = (const float*)d_in[6];
    const float* p_gn_w = (const float*)d_in[7];
    const float* p_gn_b = (const float*)d_in[8];
    const float* r_w    = (const float*)d_in[9];
    const float* r_b    = (const float*)d_in[10];
    const float* r_gn_w = (const float*)d_in[11];
    const float* r_gn_b = (const float*)d_in[12];
    const float* e1_w   = (const float*)d_in[13];
    const float* e1_b   = (const float*)d_in[14];
    const float* e2_w   = (const float*)d_in[15];
    const float* e2_b   = (const float*)d_in[16];
    const float* gamma  = (const float*)d_in[17];
    const float* beta   = (const float*)d_in[18];

    float*  gnn   = (float*)d_ws;
    double* stats = (double*)((char*)d_ws + (size_t)8 * C4 * HW * sizeof(float));

    hipMemsetAsync(stats, 0, 32 * sizeof(double), stream);
    win_kernel<<<NWIN, 256, 0, stream>>>(x_in, f_w, f_b, f_gn_w, f_gn_b,
                                         e1_w, e1_b, e2_w, e2_b, gamma, beta, gnn);
    stats_kernel<<<1568, 256, 0, stream>>>(x_in, r_w, r_b, gnn, p_w, p_b, stats);
    final_kernel<<<784, 256, 0, stream>>>(x_in, gnn, r_w, r_b, r_gn_w, r_gn_b,
                                          p_w, p_b, p_gn_w, p_gn_b, stats, (float*)d_out);
}

// Round 3
// 448.117 us; speedup vs baseline: 1.4175x; 1.1492x over previous
//
#include <hip/hip_runtime.h>
#include <math.h>

#define CIN 128
#define C4  32
#define HW  12544      // 112*112
#define NPIX 256       // nodes per window
#define KNB 9
#define NWIN 392       // 8 * 7 * 7

__device__ inline double wave_sum(double v) {
#pragma unroll
    for (int off = 32; off; off >>= 1) v += __shfl_down(v, off);
    return v;
}

// predicated stable insert: strict '>' keeps earlier-inserted on ties (== lax.top_k)
#define TOP9_INSERT(sv, mi, tv, ti)                                  \
    {                                                                \
        _Pragma("unroll")                                            \
        for (int j = KNB - 1; j >= 1; --j) {                         \
            bool cj  = (sv) > tv[j];                                 \
            bool cjm = (sv) > tv[j - 1];                             \
            tv[j] = cj ? (cjm ? tv[j - 1] : (sv)) : tv[j];           \
            ti[j] = cj ? (cjm ? ti[j - 1] : (mi)) : ti[j];           \
        }                                                            \
        bool c0 = (sv) > tv[0];                                      \
        tv[0] = c0 ? (sv) : tv[0];                                   \
        ti[0] = c0 ? (mi) : ti[0];                                   \
    }

// ---------------- window pipeline: 512 threads = (node n, segment s) ----------------
// LDS layout (62336 B, 2 blocks/CU):
//   [0,36864)      xf[256][36] fp32      (phase1: wbufd double[64][32][2] = 32768 overlaps)
//   [36864,38912)  invn[256] fp64
//   [38912,39040)  red[16] fp64
//   [39040,48256)  Mv[256][9] fp32       (after merge: e1w[2048] fp32 = 8192)
//   [48256,57472)  Mi[256][9] int32      (after merge: Wt[256][9] fp32)
//   [57472,62080)  Ti[256][9] int16
//   [62080,62336)  e1b[32], e2w[32] fp32
__global__ __launch_bounds__(512, 4) void win_kernel(
    const float* __restrict__ x_in,
    const float* __restrict__ f_w, const float* __restrict__ f_b,
    const float* __restrict__ f_gn_w, const float* __restrict__ f_gn_b,
    const float* __restrict__ e1_w, const float* __restrict__ e1_b,
    const float* __restrict__ e2_w, const float* __restrict__ e2_b,
    const float* __restrict__ gamma, const float* __restrict__ beta,
    float* __restrict__ gnn)
{
    __shared__ __align__(16) char smem[62336];
    float  (*xf)[36] = (float(*)[36])smem;
    double* wbufd  = (double*)smem;
    double* invn   = (double*)(smem + 36864);
    double* red    = (double*)(smem + 38912);
    float*  Mv     = (float*)(smem + 39040);
    int*    Mi     = (int*)  (smem + 48256);
    short*  Ti     = (short*)(smem + 57472);
    float*  e1w    = (float*)(smem + 39040);   // overlay Mv (after merge)
    float*  Wt     = (float*)(smem + 48256);   // overlay Mi (after merge)
    float*  e1b_s  = (float*)(smem + 62080);
    float*  e2w_s  = (float*)(smem + 62208);

    const int win = blockIdx.x;
    const int b   = win / 49;
    const int wg  = (win / 7) % 7;
    const int hg  = win % 7;
    const int t   = threadIdx.x;
    const int n   = t & 255;
    const int s   = t >> 8;
    const int py  = n >> 4, px = n & 15;

    // P0: stage f_w as fp64, paired-c layout wbufd[c>>1][o][c&1]
    for (int i = t; i < C4 * CIN; i += 512) {
        int o = i >> 7, c = i & 127;
        wbufd[(c >> 1) * 64 + o * 2 + (c & 1)] = (double)f_w[i];
    }
    if (t < C4) { e1b_s[t] = e1_b[t]; e2w_s[t] = e2_w[t]; }
    __syncthreads();

    // P1: f-conv, 16 output channels per thread, fp64 acc (bit-identical c-ascending chains)
    const float* xb = x_in + (size_t)b * CIN * HW + (size_t)(wg * 16 + py) * 112 + (hg * 16 + px);
    double acc[16];
#pragma unroll
    for (int j = 0; j < 16; ++j) acc[j] = 0.0;
    {
        const double2* wrow = (const double2*)wbufd + 16 * s;
        for (int c2 = 0; c2 < 64; ++c2) {
            double xv0 = (double)xb[(size_t)(2 * c2) * HW];
            double xv1 = (double)xb[(size_t)(2 * c2 + 1) * HW];
            const double2* wr = wrow + c2 * 32;
#pragma unroll
            for (int j = 0; j < 16; ++j) {
                double2 w2 = wr[j];
                acc[j] = fma(w2.x, xv0, acc[j]);
                acc[j] = fma(w2.y, xv1, acc[j]);
            }
        }
    }
    double s1 = 0.0, s2 = 0.0;
#pragma unroll
    for (int j = 0; j < 16; ++j) {
        double v = acc[j] + (double)f_b[16 * s + j];
        acc[j] = v; s1 += v; s2 += v * v;
    }
    s1 = wave_sum(s1); s2 = wave_sum(s2);
    {
        int w = t >> 6;
        if ((t & 63) == 0) { red[w] = s1; red[8 + w] = s2; }
    }
    __syncthreads();   // also fences wbufd reads before xf overwrites
    double rs1 = 0.0, rs2 = 0.0;
#pragma unroll
    for (int w = 0; w < 8; ++w) { rs1 += red[w]; rs2 += red[8 + w]; }
    const double mu   = rs1 * (1.0 / 8192.0);
    const double var  = rs2 * (1.0 / 8192.0) - mu * mu;
    const double rstd = 1.0 / sqrt(var + 1e-5);

#pragma unroll
    for (int j = 0; j < 16; ++j) {
        int c = 16 * s + j;
        float v = (float)((acc[j] - mu) * rstd * (double)f_gn_w[c] + (double)f_gn_b[c]);
        xf[n][c] = v;
    }
    const double ginv = 1.0 / (sqrt(5440.0 / 255.0) + 1e-5);   // 1/(grid std ddof=1 + eps)
    const float gyf = (float)(((double)py - 7.5) * ginv);
    const float gxf = (float)(((double)px - 7.5) * ginv);
    if (s == 0) { xf[n][32] = gyf; xf[n][33] = gxf; xf[n][34] = 0.f; xf[n][35] = 0.f; }
    __syncthreads();

    // P2: full row into fp64 regs + inverse norm
    double xad[36];
#pragma unroll
    for (int c = 0; c < C4; ++c) xad[c] = (double)xf[n][c];
    xad[32] = (double)gyf; xad[33] = (double)gxf; xad[34] = 0.0; xad[35] = 0.0;
    double nrm = 0.0;
#pragma unroll
    for (int c = 0; c < 34; ++c) nrm += xad[c] * xad[c];
    const double inv = 1.0 / fmax(sqrt(nrm), 1e-8);
    if (s == 0) invn[n] = inv;
    __syncthreads();

    // P3: sim over this segment's half of m + local top-9
    const double inv_self = inv;
    float tv[KNB]; int ti[KNB];
#pragma unroll
    for (int k = 0; k < KNB; ++k) { tv[k] = -INFINITY; ti[k] = 0; }
    const int m0 = s * 128;
#pragma unroll 2
    for (int mm = 0; mm < 128; ++mm) {
        const int m = m0 + mm;
        const float4* xm = (const float4*)xf[m];
        double d0 = 0.0, d1 = 0.0, d2 = 0.0, d3 = 0.0;
#pragma unroll
        for (int q = 0; q < 9; ++q) {
            float4 f = xm[q];
            d0 = fma((double)f.x, xad[q * 4 + 0], d0);
            d1 = fma((double)f.y, xad[q * 4 + 1], d1);
            d2 = fma((double)f.z, xad[q * 4 + 2], d2);
            d3 = fma((double)f.w, xad[q * 4 + 3], d3);
        }
        double d = (d0 + d1) + (d2 + d3);
        float sv = (float)(d * (inv_self * invn[m]));
        sv = (m == n) ? -INFINITY : sv;
        TOP9_INSERT(sv, m, tv, ti);
    }

    // P4: seg1 publishes, seg0 merges (seg1 indices all > seg0's; strict '>' keeps low idx on ties)
    if (s == 1) {
#pragma unroll
        for (int k = 0; k < KNB; ++k) { Mv[n * 9 + k] = tv[k]; Mi[n * 9 + k] = ti[k]; }
    }
    __syncthreads();
    if (s == 0) {
#pragma unroll
        for (int k = 0; k < KNB; ++k) {
            float sv = Mv[n * 9 + k];
            int   mi = Mi[n * 9 + k];
            TOP9_INSERT(sv, mi, tv, ti);
        }
#pragma unroll
        for (int k = 0; k < KNB; ++k) Ti[n * 9 + k] = (short)ti[k];
    }
    __syncthreads();
    // e1w overlays Mv (merge reads done)
    for (int i = t; i < 2048; i += 512) e1w[i] = e1_w[i];
    __syncthreads();

    // P5: edge MLP. hs = src-half (per node); neighbors split 5/4 across segments.
    float hs[C4];
    {
        float xfn[C4];
#pragma unroll
        for (int c = 0; c < C4; ++c) xfn[c] = xf[n][c];
#pragma unroll 2
        for (int j = 0; j < C4; ++j) {
            const float4* er = (const float4*)(e1w + j * 64);
            float h0 = e1b_s[j], h1 = 0.f;
#pragma unroll
            for (int q = 0; q < 8; ++q) {
                float4 f = er[q];
                h0 = fmaf(f.x, xfn[q * 4 + 0], h0);
                h1 = fmaf(f.y, xfn[q * 4 + 1], h1);
                h0 = fmaf(f.z, xfn[q * 4 + 2], h0);
                h1 = fmaf(f.w, xfn[q * 4 + 3], h1);
            }
            hs[j] = h0 + h1;
        }
    }
    const float e2b = e2_b[0];
    const int k0 = s ? 5 : 0, k1 = s ? KNB : 5;
    for (int k = k0; k < k1; ++k) {
        const int mm = Ti[n * 9 + k];
        float msg[C4];
        const float4* xm = (const float4*)xf[mm];
#pragma unroll
        for (int q = 0; q < 8; ++q) {
            float4 f = xm[q];
            msg[q * 4 + 0] = f.x; msg[q * 4 + 1] = f.y;
            msg[q * 4 + 2] = f.z; msg[q * 4 + 3] = f.w;
        }
        float a2 = 0.f;
#pragma unroll 2
        for (int j = 0; j < C4; ++j) {
            const float4* er = (const float4*)(e1w + j * 64 + 32);
            float h0 = hs[j], h1 = 0.f;
#pragma unroll
            for (int q = 0; q < 8; ++q) {
                float4 f = er[q];
                h0 = fmaf(f.x, msg[q * 4 + 0], h0);
                h1 = fmaf(f.y, msg[q * 4 + 1], h1);
                h0 = fmaf(f.z, msg[q * 4 + 2], h0);
                h1 = fmaf(f.w, msg[q * 4 + 3], h1);
            }
            float h = h0 + h1;
            float sg = 1.f / (1.f + __expf(-h));      // silu = h*sigmoid(h)
            a2 = fmaf(e2w_s[j], h * sg, a2);
        }
        Wt[n * 9 + k] = 1.f / (1.f + __expf(-(a2 + e2b)));
    }
    __syncthreads();

    // P6: aggregate 16 channels per thread, write gnn
    short tis[KNB]; float wks[KNB];
#pragma unroll
    for (int k = 0; k < KNB; ++k) { tis[k] = Ti[n * 9 + k]; wks[k] = Wt[n * 9 + k]; }
    const float g = gamma[0], be = beta[0];
    float* gp = gnn + (size_t)b * C4 * HW + (size_t)(wg * 16 + py) * 112 + (hg * 16 + px);
#pragma unroll
    for (int qq = 0; qq < 4; ++qq) {
        const int q = 4 * s + qq;
        float4 o = {0.f, 0.f, 0.f, 0.f};
#pragma unroll
        for (int k = 0; k < KNB; ++k) {
            float4 f = ((const float4*)xf[tis[k]])[q];
            o.x = fmaf(wks[k], f.x, o.x);
            o.y = fmaf(wks[k], f.y, o.y);
            o.z = fmaf(wks[k], f.z, o.z);
            o.w = fmaf(wks[k], f.w, o.w);
        }
        gp[(size_t)(q * 4 + 0) * HW] = fmaf(g, o.x, be * xf[n][q * 4 + 0]);
        gp[(size_t)(q * 4 + 1) * HW] = fmaf(g, o.y, be * xf[n][q * 4 + 1]);
        gp[(size_t)(q * 4 + 2) * HW] = fmaf(g, o.z, be * xf[n][q * 4 + 2]);
        gp[(size_t)(q * 4 + 3) * HW] = fmaf(g, o.w, be * xf[n][q * 4 + 3]);
    }
}

// ---------------- merged conv stats: blocks [0,784) r-conv, [784,1568) p-conv ----------------
__global__ __launch_bounds__(256, 2) void stats_kernel(
    const float* __restrict__ x_in,
    const float* __restrict__ r_w, const float* __restrict__ r_b,
    const float* __restrict__ gnn,
    const float* __restrict__ p_w, const float* __restrict__ p_b,
    double* __restrict__ stats)
{
    __shared__ float  wt[64 * CIN];   // [c][o'] 32KB (r); p uses first 8KB
    __shared__ double red[8];
    const int idx = blockIdx.x;
    const int t   = threadIdx.x;
    double s1 = 0.0, s2 = 0.0;
    int sslot;

    if (idx < 784) {
        const int b = idx / 98, rem = idx % 98;
        const int oc = rem / 49, pg = rem % 49;
        for (int i = t; i < 64 * CIN; i += 256)
            wt[(i & 127) * 64 + (i >> 7)] = r_w[oc * 64 * CIN + i];
        __syncthreads();
        const float* xb = x_in + (size_t)b * CIN * HW + pg * 256 + t;
        float acc[64];
#pragma unroll
        for (int o = 0; o < 64; ++o) acc[o] = r_b[oc * 64 + o];
        for (int c0 = 0; c0 < CIN; c0 += 8) {
            float xv[8];
#pragma unroll
            for (int u = 0; u < 8; ++u) xv[u] = xb[(size_t)(c0 + u) * HW];
#pragma unroll
            for (int u = 0; u < 8; ++u)
#pragma unroll
                for (int o = 0; o < 64; ++o) acc[o] = fmaf(wt[(c0 + u) * 64 + o], xv[u], acc[o]);
        }
#pragma unroll
        for (int o = 0; o < 64; ++o) { double v = (double)acc[o]; s1 += v; s2 += v * v; }
        sslot = b * 4;
    } else {
        const int i2 = idx - 784;
        const int b = i2 / 98, rem = i2 % 98;
        const int oc = rem / 49, pg = rem % 49;
        for (int i = t; i < 64 * C4; i += 256)
            wt[(i & 31) * 64 + (i >> 5)] = p_w[oc * 64 * C4 + i];
        __syncthreads();
        const float* gb = gnn + (size_t)b * C4 * HW + pg * 256 + t;
        float xg[C4];
#pragma unroll
        for (int c = 0; c < C4; ++c) xg[c] = gb[(size_t)c * HW];
        float acc[64];
#pragma unroll
        for (int o = 0; o < 64; ++o) acc[o] = p_b[oc * 64 + o];
#pragma unroll
        for (int c = 0; c < C4; ++c)
#pragma unroll
            for (int o = 0; o < 64; ++o) acc[o] = fmaf(wt[c * 64 + o], xg[c], acc[o]);
#pragma unroll
        for (int o = 0; o < 64; ++o) { double v = (double)acc[o]; s1 += v; s2 += v * v; }
        sslot = b * 4 + 2;
    }
    s1 = wave_sum(s1); s2 = wave_sum(s2);
    if ((t & 63) == 0) { red[t >> 6] = s1; red[4 + (t >> 6)] = s2; }
    __syncthreads();
    if (t == 0) {
        atomicAdd(&stats[sslot + 0], red[0] + red[1] + red[2] + red[3]);
        atomicAdd(&stats[sslot + 1], red[4] + red[5] + red[6] + red[7]);
    }
}

// ---------------- final: GN(r conv) + GN(p conv) + add, split by 64-out chunk ----------------
__global__ __launch_bounds__(256, 2) void final_kernel(
    const float* __restrict__ x_in, const float* __restrict__ gnn,
    const float* __restrict__ r_w, const float* __restrict__ r_b,
    const float* __restrict__ r_gn_w, const float* __restrict__ r_gn_b,
    const float* __restrict__ p_w, const float* __restrict__ p_b,
    const float* __restrict__ p_gn_w, const float* __restrict__ p_gn_b,
    const double* __restrict__ stats,
    float* __restrict__ out)
{
    __shared__ float rwt[64 * CIN];   // 32KB [c][o']
    __shared__ float pwt[64 * C4];    // 8KB  [c][o']
    const int idx = blockIdx.x;
    const int b = idx / 98, rem = idx % 98;
    const int oc = rem / 49, pg = rem % 49;
    const int t = threadIdx.x;

    for (int i = t; i < 64 * CIN; i += 256)
        rwt[(i & 127) * 64 + (i >> 7)] = r_w[oc * 64 * CIN + i];
    for (int i = t; i < 64 * C4; i += 256)
        pwt[(i & 31) * 64 + (i >> 5)] = p_w[oc * 64 * C4 + i];
    __syncthreads();

    const double NN = (double)CIN * HW;
    const double mu_r = stats[b * 4 + 0] / NN;
    const float  rs_r = (float)(1.0 / sqrt(stats[b * 4 + 1] / NN - mu_r * mu_r + 1e-5));
    const double mu_p = stats[b * 4 + 2] / NN;
    const float  rs_p = (float)(1.0 / sqrt(stats[b * 4 + 3] / NN - mu_p * mu_p + 1e-5));
    const float fmur = (float)mu_r, fmup = (float)mu_p;

    const int p = pg * 256 + t;
    const float* xb = x_in + (size_t)b * CIN * HW + p;
    const float* gb = gnn + (size_t)b * C4 * HW + p;
    float* ob = out + (size_t)b * CIN * HW + p;

    float xg[C4];
#pragma unroll
    for (int c = 0; c < C4; ++c) xg[c] = gb[(size_t)c * HW];

    float accR[64], accP[64];
#pragma unroll
    for (int o = 0; o < 64; ++o) { accR[o] = r_b[oc * 64 + o]; accP[o] = p_b[oc * 64 + o]; }
    for (int c0 = 0; c0 < CIN; c0 += 8) {
        float xv[8];
#pragma unroll
        for (int u = 0; u < 8; ++u) xv[u] = xb[(size_t)(c0 + u) * HW];
#pragma unroll
        for (int u = 0; u < 8; ++u)
#pragma unroll
            for (int o = 0; o < 64; ++o) accR[o] = fmaf(rwt[(c0 + u) * 64 + o], xv[u], accR[o]);
    }
#pragma unroll
    for (int c = 0; c < C4; ++c)
#pragma unroll
        for (int o = 0; o < 64; ++o) accP[o] = fmaf(pwt[c * 64 + o], xg[c], accP[o]);

#pragma unroll
    for (int o = 0; o < 64; ++o) {
        const int O = oc * 64 + o;
        float yr = (accR[o] - fmur) * rs_r * r_gn_w[O] + r_gn_b[O];
        float yp = (accP[o] - fmup) * rs_p * p_gn_w[O] + p_gn_b[O];
        ob[(size_t)O * HW] = yp + yr;
    }
}

extern "C" void kernel_launch(void* const* d_in, const int* in_sizes, int n_in,
                              void* d_out, int out_size, void* d_ws, size_t ws_size,
                              hipStream_t stream)
{
    const float* x_in   = (const float*)d_in[0];
    const float* f_w    = (const float*)d_in[1];
    const float* f_b    = (const float*)d_in[2];
    const float* f_gn_w = (const float*)d_in[3];
    const float* f_gn_b = (const float*)d_in[4];
    const float* p_w    = (const float*)d_in[5];
    const float* p_b    = (const float*)d_in[6];
    const float* p_gn_w = (const float*)d_in[7];
    const float* p_gn_b = (const float*)d_in[8];
    const float* r_w    = (const float*)d_in[9];
    const float* r_b    = (const float*)d_in[10];
    const float* r_gn_w = (const float*)d_in[11];
    const float* r_gn_b = (const float*)d_in[12];
    const float* e1_w   = (const float*)d_in[13];
    const float* e1_b   = (const float*)d_in[14];
    const float* e2_w   = (const float*)d_in[15];
    const float* e2_b   = (const float*)d_in[16];
    const float* gamma  = (const float*)d_in[17];
    const float* beta   = (const float*)d_in[18];

    float*  gnn   = (float*)d_ws;
    double* stats = (double*)((char*)d_ws + (size_t)8 * C4 * HW * sizeof(float));

    hipMemsetAsync(stats, 0, 32 * sizeof(double), stream);
    win_kernel<<<NWIN, 512, 0, stream>>>(x_in, f_w, f_b, f_gn_w, f_gn_b,
                                         e1_w, e1_b, e2_w, e2_b, gamma, beta, gnn);
    stats_kernel<<<1568, 256, 0, stream>>>(x_in, r_w, r_b, gnn, p_w, p_b, stats);
    final_kernel<<<784, 256, 0, stream>>>(x_in, gnn, r_w, r_b, r_gn_w, r_gn_b,
                                          p_w, p_b, p_gn_w, p_gn_b, stats, (float*)d_out);
}

// Round 4
// 432.127 us; speedup vs baseline: 1.4699x; 1.0370x over previous
//
#include <hip/hip_runtime.h>
#include <math.h>

#define CIN 128
#define C4  32
#define HW  12544      // 112*112
#define NPIX 256       // nodes per window
#define KNB 9
#define NWIN 392       // 8 * 7 * 7

__device__ inline double wave_sum(double v) {
#pragma unroll
    for (int off = 32; off; off >>= 1) v += __shfl_down(v, off);
    return v;
}

// predicated stable insert: strict '>' keeps earlier-inserted on ties (== lax.top_k)
#define TOP9_INSERT(sv, mi, tv, ti)                                  \
    {                                                                \
        _Pragma("unroll")                                            \
        for (int j = KNB - 1; j >= 1; --j) {                         \
            bool cj  = (sv) > tv[j];                                 \
            bool cjm = (sv) > tv[j - 1];                             \
            tv[j] = cj ? (cjm ? tv[j - 1] : (sv)) : tv[j];           \
            ti[j] = cj ? (cjm ? ti[j - 1] : (mi)) : ti[j];           \
        }                                                            \
        bool c0 = (sv) > tv[0];                                      \
        tv[0] = c0 ? (sv) : tv[0];                                   \
        ti[0] = c0 ? (mi) : ti[0];                                   \
    }

// ================= K1: fconv (blocks 0..391) + r-stats (blocks 392..1175) =================
__global__ __launch_bounds__(512, 2) void fconv_rstats_kernel(
    const float* __restrict__ x_in,
    const float* __restrict__ f_w, const float* __restrict__ f_b,
    const float* __restrict__ f_gn_w, const float* __restrict__ f_gn_b,
    const float* __restrict__ r_w, const float* __restrict__ r_b,
    float* __restrict__ xfws, double* __restrict__ invnws,
    double* __restrict__ stats)
{
    __shared__ __align__(16) char smem[34944];
    const int t = threadIdx.x;

    if (blockIdx.x < NWIN) {
        // ---- fconv + GN -> xf (global), invn (global) ----
        double* wbufd = (double*)smem;              // [0,32768) f_w as fp64 paired-c
        double* vbuf  = (double*)smem;              // reuse: [256][17] fp64 (34816B)
        double* red   = (double*)(smem + 34816);    // 16 fp64
        const int win = blockIdx.x;
        const int b = win / 49, wg = (win / 7) % 7, hg = win % 7;
        const int n = t & 255, s = t >> 8;
        const int py = n >> 4, px = n & 15;

        for (int i = t; i < C4 * CIN; i += 512) {
            int o = i >> 7, c = i & 127;
            wbufd[(c >> 1) * 64 + o * 2 + (c & 1)] = (double)f_w[i];
        }
        __syncthreads();

        const float* xb = x_in + (size_t)b * CIN * HW + (size_t)(wg * 16 + py) * 112 + (hg * 16 + px);
        double acc[16];
#pragma unroll
        for (int j = 0; j < 16; ++j) acc[j] = 0.0;
        {
            const double2* wrow = (const double2*)wbufd + 16 * s;
            for (int c2 = 0; c2 < 64; ++c2) {
                double xv0 = (double)xb[(size_t)(2 * c2) * HW];
                double xv1 = (double)xb[(size_t)(2 * c2 + 1) * HW];
                const double2* wr = wrow + c2 * 32;
#pragma unroll
                for (int j = 0; j < 16; ++j) {
                    double2 w2 = wr[j];
                    acc[j] = fma(w2.x, xv0, acc[j]);
                    acc[j] = fma(w2.y, xv1, acc[j]);
                }
            }
        }
        double s1 = 0.0, s2 = 0.0;
#pragma unroll
        for (int j = 0; j < 16; ++j) {
            double v = acc[j] + (double)f_b[16 * s + j];
            acc[j] = v; s1 += v; s2 += v * v;
        }
        s1 = wave_sum(s1); s2 = wave_sum(s2);
        {
            int w = t >> 6;
            if ((t & 63) == 0) { red[w] = s1; red[8 + w] = s2; }
        }
        __syncthreads();   // fences wbufd reads too
        double rs1 = 0.0, rs2 = 0.0;
#pragma unroll
        for (int w = 0; w < 8; ++w) { rs1 += red[w]; rs2 += red[8 + w]; }
        const double mu   = rs1 * (1.0 / 8192.0);
        const double var  = rs2 * (1.0 / 8192.0) - mu * mu;
        const double rstd = 1.0 / sqrt(var + 1e-5);

        float myv[16];
#pragma unroll
        for (int j = 0; j < 16; ++j) {
            int c = 16 * s + j;
            myv[j] = (float)((acc[j] - mu) * rstd * (double)f_gn_w[c] + (double)f_gn_b[c]);
        }
        float* xrow = xfws + (size_t)(win * 256 + n) * 36;
#pragma unroll
        for (int q4 = 0; q4 < 4; ++q4) {
            float4 f = { myv[4 * q4], myv[4 * q4 + 1], myv[4 * q4 + 2], myv[4 * q4 + 3] };
            ((float4*)(xrow + 16 * s))[q4] = f;
        }
        const double ginv = 1.0 / (sqrt(5440.0 / 255.0) + 1e-5);
        const float gyf = (float)(((double)py - 7.5) * ginv);
        const float gxf = (float)(((double)px - 7.5) * ginv);
        if (s == 0) {
            float4 g4 = { gyf, gxf, 0.f, 0.f };
            ((float4*)(xrow + 32))[0] = g4;
        }
        // exchange s1-half values for bit-identical sequential norm (c = 0..33)
        if (s == 1) {
#pragma unroll
            for (int j = 0; j < 16; ++j) vbuf[n * 17 + j] = (double)myv[j];
        }
        __syncthreads();
        if (s == 0) {
            double nrm = 0.0;
#pragma unroll
            for (int j = 0; j < 16; ++j) { double x = (double)myv[j]; nrm += x * x; }
#pragma unroll
            for (int j = 0; j < 16; ++j) { double x = vbuf[n * 17 + j]; nrm += x * x; }
            double xg = (double)gyf; nrm += xg * xg;
            double xh = (double)gxf; nrm += xh * xh;
            invnws[win * 256 + n] = 1.0 / fmax(sqrt(nrm), 1e-8);
        }
    } else {
        // ---- r-conv stats ----
        float*  wt  = (float*)smem;                 // 32KB [c][64]
        double* red = (double*)(smem + 34816);
        const int idx = blockIdx.x - NWIN;
        const int b = idx / 98, rem = idx % 98;
        const int oc = rem / 49, pg = rem % 49;
        const int sh = t >> 8, n = t & 255;
        for (int i = t; i < 64 * CIN; i += 512)
            wt[(i & 127) * 64 + (i >> 7)] = r_w[oc * 64 * CIN + i];
        __syncthreads();
        const float* xb = x_in + (size_t)b * CIN * HW + pg * 256 + n;
        float acc[32];
#pragma unroll
        for (int o = 0; o < 32; ++o) acc[o] = r_b[oc * 64 + sh * 32 + o];
        for (int c0 = 0; c0 < CIN; c0 += 8) {
            float xv[8];
#pragma unroll
            for (int u = 0; u < 8; ++u) xv[u] = xb[(size_t)(c0 + u) * HW];
#pragma unroll
            for (int u = 0; u < 8; ++u)
#pragma unroll
                for (int o = 0; o < 32; ++o)
                    acc[o] = fmaf(wt[(c0 + u) * 64 + sh * 32 + o], xv[u], acc[o]);
        }
        double s1 = 0.0, s2 = 0.0;
#pragma unroll
        for (int o = 0; o < 32; ++o) { double v = (double)acc[o]; s1 += v; s2 += v * v; }
        s1 = wave_sum(s1); s2 = wave_sum(s2);
        {
            int w = t >> 6;
            if ((t & 63) == 0) { red[w] = s1; red[8 + w] = s2; }
        }
        __syncthreads();
        if (t == 0) {
            double a = 0.0, c = 0.0;
#pragma unroll
            for (int w = 0; w < 8; ++w) { a += red[w]; c += red[8 + w]; }
            atomicAdd(&stats[b * 4 + 0], a);
            atomicAdd(&stats[b * 4 + 1], c);
        }
    }
}

// ================= K2: sim + partial top-9, block = (window, m-quarter) =================
__global__ __launch_bounds__(256, 4) void sim_kernel(
    const float* __restrict__ xfws, const double* __restrict__ invnws,
    float* __restrict__ pval, short* __restrict__ pidx)
{
    __shared__ __align__(16) float xfm[64 * 36];   // 64 m-rows
    __shared__ double invm[64];
    const int bid = blockIdx.x;
    const int win = bid >> 2, m0 = (bid & 3) << 6;
    const int n = threadIdx.x;

    const float* src = xfws + (size_t)(win * 256 + m0) * 36;
    for (int i = n; i < 64 * 36; i += 256) xfm[i] = src[i];
    if (n < 64) invm[n] = invnws[win * 256 + m0 + n];

    double xad[36];
    {
        const float4* own = (const float4*)(xfws + (size_t)(win * 256 + n) * 36);
#pragma unroll
        for (int q = 0; q < 9; ++q) {
            float4 f = own[q];
            xad[q * 4 + 0] = (double)f.x; xad[q * 4 + 1] = (double)f.y;
            xad[q * 4 + 2] = (double)f.z; xad[q * 4 + 3] = (double)f.w;
        }
    }
    const double inv_self = invnws[win * 256 + n];
    __syncthreads();

    float tv[KNB]; int ti[KNB];
#pragma unroll
    for (int k = 0; k < KNB; ++k) { tv[k] = -INFINITY; ti[k] = 0; }
#pragma unroll 2
    for (int mm = 0; mm < 64; ++mm) {
        const int m = m0 + mm;
        const float4* xm = (const float4*)(xfm + mm * 36);
        double d0 = 0.0, d1 = 0.0, d2 = 0.0, d3 = 0.0;
#pragma unroll
        for (int q = 0; q < 9; ++q) {
            float4 f = xm[q];
            d0 = fma((double)f.x, xad[q * 4 + 0], d0);
            d1 = fma((double)f.y, xad[q * 4 + 1], d1);
            d2 = fma((double)f.z, xad[q * 4 + 2], d2);
            d3 = fma((double)f.w, xad[q * 4 + 3], d3);
        }
        double d = (d0 + d1) + (d2 + d3);
        float sv = (float)(d * (inv_self * invm[mm]));
        sv = (m == n) ? -INFINITY : sv;
        TOP9_INSERT(sv, m, tv, ti);
    }
    const size_t base = ((size_t)bid * 256 + n) * 9;
#pragma unroll
    for (int k = 0; k < KNB; ++k) { pval[base + k] = tv[k]; pidx[base + k] = (short)ti[k]; }
}

// ================= K3: merge quarters + edge MLP + aggregate + p-stats =================
__global__ __launch_bounds__(512, 2) void merge_mlp_kernel(
    const float* __restrict__ xfws,
    const float* __restrict__ pval, const short* __restrict__ pidx,
    const float* __restrict__ e1_w, const float* __restrict__ e1_b,
    const float* __restrict__ e2_w, const float* __restrict__ e2_b,
    const float* __restrict__ gamma, const float* __restrict__ beta,
    const float* __restrict__ p_w, const float* __restrict__ p_b,
    float* __restrict__ gnn, double* __restrict__ stats)
{
    __shared__ __align__(16) char smem[59264];
    float (*xf)[36] = (float(*)[36])smem;          // [0,36864)
    float* e1w   = (float*)(smem + 36864);         // 8192
    short* Ti    = (short*)(smem + 45056);         // 4608
    float* Wt    = (float*)(smem + 49664);         // 9216
    float* e1b_s = (float*)(smem + 58880);
    float* e2w_s = (float*)(smem + 59008);
    double* red  = (double*)(smem + 59136);        // 16 fp64
    float* pwt   = (float*)smem;                   // overlay after agg: [c][128] 16KB
    float* gnx   = (float*)(smem + 16384);         // overlay: [256][33] = 33792B

    const int win = blockIdx.x;
    const int b = win / 49, wg = (win / 7) % 7, hg = win % 7;
    const int t = threadIdx.x, n = t & 255, s = t >> 8;
    const int py = n >> 4, px = n & 15;

    const float* src = xfws + (size_t)win * 256 * 36;
    for (int i = t; i < 256 * 36; i += 512) ((float*)xf)[i] = src[i];
    for (int i = t; i < 2048; i += 512) e1w[i] = e1_w[i];
    if (t < C4) { e1b_s[t] = e1_b[t]; e2w_s[t] = e2_w[t]; }
    __syncthreads();

    // merge 4 quarter lists (ascending qd == ascending m => stable == lax.top_k)
    if (s == 0) {
        float tv[KNB]; int ti[KNB];
#pragma unroll
        for (int k = 0; k < KNB; ++k) { tv[k] = -INFINITY; ti[k] = 0; }
        for (int qd = 0; qd < 4; ++qd) {
            const size_t base = ((size_t)(win * 4 + qd) * 256 + n) * 9;
#pragma unroll
            for (int k = 0; k < KNB; ++k) {
                float sv = pval[base + k];
                int   mi = (int)pidx[base + k];
                TOP9_INSERT(sv, mi, tv, ti);
            }
        }
#pragma unroll
        for (int k = 0; k < KNB; ++k) Ti[n * 9 + k] = (short)ti[k];
    }
    __syncthreads();

    // edge MLP (unchanged arithmetic)
    float hs[C4];
    {
        float xfn[C4];
#pragma unroll
        for (int c = 0; c < C4; ++c) xfn[c] = xf[n][c];
#pragma unroll 2
        for (int j = 0; j < C4; ++j) {
            const float4* er = (const float4*)(e1w + j * 64);
            float h0 = e1b_s[j], h1 = 0.f;
#pragma unroll
            for (int q = 0; q < 8; ++q) {
                float4 f = er[q];
                h0 = fmaf(f.x, xfn[q * 4 + 0], h0);
                h1 = fmaf(f.y, xfn[q * 4 + 1], h1);
                h0 = fmaf(f.z, xfn[q * 4 + 2], h0);
                h1 = fmaf(f.w, xfn[q * 4 + 3], h1);
            }
            hs[j] = h0 + h1;
        }
    }
    const float e2b = e2_b[0];
    const int k0 = s ? 5 : 0, k1 = s ? KNB : 5;
    for (int k = k0; k < k1; ++k) {
        const int mm = (int)Ti[n * 9 + k];
        float msg[C4];
        const float4* xm = (const float4*)xf[mm];
#pragma unroll
        for (int q = 0; q < 8; ++q) {
            float4 f = xm[q];
            msg[q * 4 + 0] = f.x; msg[q * 4 + 1] = f.y;
            msg[q * 4 + 2] = f.z; msg[q * 4 + 3] = f.w;
        }
        float a2 = 0.f;
#pragma unroll 2
        for (int j = 0; j < C4; ++j) {
            const float4* er = (const float4*)(e1w + j * 64 + 32);
            float h0 = hs[j], h1 = 0.f;
#pragma unroll
            for (int q = 0; q < 8; ++q) {
                float4 f = er[q];
                h0 = fmaf(f.x, msg[q * 4 + 0], h0);
                h1 = fmaf(f.y, msg[q * 4 + 1], h1);
                h0 = fmaf(f.z, msg[q * 4 + 2], h0);
                h1 = fmaf(f.w, msg[q * 4 + 3], h1);
            }
            float h = h0 + h1;
            float sg = 1.f / (1.f + __expf(-h));
            a2 = fmaf(e2w_s[j], h * sg, a2);
        }
        Wt[n * 9 + k] = 1.f / (1.f + __expf(-(a2 + e2b)));
    }
    __syncthreads();

    // aggregate 16 channels per thread, write gnn, keep values for p-stats
    short tis[KNB]; float wks[KNB];
#pragma unroll
    for (int k = 0; k < KNB; ++k) { tis[k] = Ti[n * 9 + k]; wks[k] = Wt[n * 9 + k]; }
    const float g = gamma[0], be = beta[0];
    float gl[16];
    float* gp = gnn + (size_t)b * C4 * HW + (size_t)(wg * 16 + py) * 112 + (hg * 16 + px);
#pragma unroll
    for (int qq = 0; qq < 4; ++qq) {
        const int q = 4 * s + qq;
        float4 o = { 0.f, 0.f, 0.f, 0.f };
#pragma unroll
        for (int k = 0; k < KNB; ++k) {
            float4 f = ((const float4*)xf[tis[k]])[q];
            o.x = fmaf(wks[k], f.x, o.x);
            o.y = fmaf(wks[k], f.y, o.y);
            o.z = fmaf(wks[k], f.z, o.z);
            o.w = fmaf(wks[k], f.w, o.w);
        }
        gl[4 * qq + 0] = fmaf(g, o.x, be * xf[n][q * 4 + 0]);
        gl[4 * qq + 1] = fmaf(g, o.y, be * xf[n][q * 4 + 1]);
        gl[4 * qq + 2] = fmaf(g, o.z, be * xf[n][q * 4 + 2]);
        gl[4 * qq + 3] = fmaf(g, o.w, be * xf[n][q * 4 + 3]);
        gp[(size_t)(q * 4 + 0) * HW] = gl[4 * qq + 0];
        gp[(size_t)(q * 4 + 1) * HW] = gl[4 * qq + 1];
        gp[(size_t)(q * 4 + 2) * HW] = gl[4 * qq + 2];
        gp[(size_t)(q * 4 + 3) * HW] = gl[4 * qq + 3];
    }
    __syncthreads();   // all xf/Wt/Ti reads complete; overlays become safe

    // p-stats from in-register gnn values
    for (int i = t; i < 4096; i += 512) pwt[(i & 31) * 128 + (i >> 5)] = p_w[i];
#pragma unroll
    for (int j = 0; j < 16; ++j) gnx[n * 33 + 16 * s + j] = gl[j];
    __syncthreads();
    float xv[32];
#pragma unroll
    for (int c = 0; c < 32; ++c) xv[c] = gnx[n * 33 + c];
    double s1 = 0.0, s2 = 0.0;
    const int o0 = 64 * s;
    for (int o = 0; o < 64; ++o) {
        float a = p_b[o0 + o];
#pragma unroll
        for (int c = 0; c < 32; ++c) a = fmaf(pwt[c * 128 + o0 + o], xv[c], a);
        s1 += (double)a; s2 += (double)a * (double)a;
    }
    s1 = wave_sum(s1); s2 = wave_sum(s2);
    {
        int w = t >> 6;
        if ((t & 63) == 0) { red[w] = s1; red[8 + w] = s2; }
    }
    __syncthreads();
    if (t == 0) {
        double a = 0.0, c = 0.0;
#pragma unroll
        for (int w = 0; w < 8; ++w) { a += red[w]; c += red[8 + w]; }
        atomicAdd(&stats[b * 4 + 2], a);
        atomicAdd(&stats[b * 4 + 3], c);
    }
}

// ================= final: GN(r)+GN(p)+add, block = (b, 32-out chunk, pixel group) =================
__global__ __launch_bounds__(256, 4) void final_kernel(
    const float* __restrict__ x_in, const float* __restrict__ gnn,
    const float* __restrict__ r_w, const float* __restrict__ r_b,
    const float* __restrict__ r_gn_w, const float* __restrict__ r_gn_b,
    const float* __restrict__ p_w, const float* __restrict__ p_b,
    const float* __restrict__ p_gn_w, const float* __restrict__ p_gn_b,
    const double* __restrict__ stats,
    float* __restrict__ out)
{
    __shared__ float rwt[32 * CIN];   // 16KB [c][32]
    __shared__ float pwt[32 * C4];    // 4KB  [c][32]
    const int idx = blockIdx.x;
    const int b = idx / 196, rem = idx % 196;
    const int ocq = rem / 49, pg = rem % 49;
    const int t = threadIdx.x;

    for (int i = t; i < 32 * CIN; i += 256)
        rwt[(i & 127) * 32 + (i >> 7)] = r_w[(size_t)(ocq * 32) * CIN + i];
    for (int i = t; i < 32 * C4; i += 256)
        pwt[(i & 31) * 32 + (i >> 5)] = p_w[(size_t)(ocq * 32) * C4 + i];
    __syncthreads();

    const double NN = (double)CIN * HW;
    const double mu_r = stats[b * 4 + 0] / NN;
    const float  rs_r = (float)(1.0 / sqrt(stats[b * 4 + 1] / NN - mu_r * mu_r + 1e-5));
    const double mu_p = stats[b * 4 + 2] / NN;
    const float  rs_p = (float)(1.0 / sqrt(stats[b * 4 + 3] / NN - mu_p * mu_p + 1e-5));
    const float fmur = (float)mu_r, fmup = (float)mu_p;

    const int p = pg * 256 + t;
    const float* xb = x_in + (size_t)b * CIN * HW + p;
    const float* gb = gnn + (size_t)b * C4 * HW + p;
    float* ob = out + (size_t)b * CIN * HW + p;

    float xg[C4];
#pragma unroll
    for (int c = 0; c < C4; ++c) xg[c] = gb[(size_t)c * HW];

    float accR[32], accP[32];
#pragma unroll
    for (int o = 0; o < 32; ++o) {
        accR[o] = r_b[ocq * 32 + o];
        accP[o] = p_b[ocq * 32 + o];
    }
    for (int c0 = 0; c0 < CIN; c0 += 8) {
        float xv[8];
#pragma unroll
        for (int u = 0; u < 8; ++u) xv[u] = xb[(size_t)(c0 + u) * HW];
#pragma unroll
        for (int u = 0; u < 8; ++u)
#pragma unroll
            for (int o = 0; o < 32; ++o)
                accR[o] = fmaf(rwt[(c0 + u) * 32 + o], xv[u], accR[o]);
    }
#pragma unroll
    for (int c = 0; c < C4; ++c)
#pragma unroll
        for (int o = 0; o < 32; ++o)
            accP[o] = fmaf(pwt[c * 32 + o], xg[c], accP[o]);

#pragma unroll
    for (int o = 0; o < 32; ++o) {
        const int O = ocq * 32 + o;
        float yr = (accR[o] - fmur) * rs_r * r_gn_w[O] + r_gn_b[O];
        float yp = (accP[o] - fmup) * rs_p * p_gn_w[O] + p_gn_b[O];
        ob[(size_t)O * HW] = yp + yr;
    }
}

extern "C" void kernel_launch(void* const* d_in, const int* in_sizes, int n_in,
                              void* d_out, int out_size, void* d_ws, size_t ws_size,
                              hipStream_t stream)
{
    const float* x_in   = (const float*)d_in[0];
    const float* f_w    = (const float*)d_in[1];
    const float* f_b    = (const float*)d_in[2];
    const float* f_gn_w = (const float*)d_in[3];
    const float* f_gn_b = (const float*)d_in[4];
    const float* p_w    = (const float*)d_in[5];
    const float* p_b    = (const float*)d_in[6];
    const float* p_gn_w = (const float*)d_in[7];
    const float* p_gn_b = (const float*)d_in[8];
    const float* r_w    = (const float*)d_in[9];
    const float* r_b    = (const float*)d_in[10];
    const float* r_gn_w = (const float*)d_in[11];
    const float* r_gn_b = (const float*)d_in[12];
    const float* e1_w   = (const float*)d_in[13];
    const float* e1_b   = (const float*)d_in[14];
    const float* e2_w   = (const float*)d_in[15];
    const float* e2_b   = (const float*)d_in[16];
    const float* gamma  = (const float*)d_in[17];
    const float* beta   = (const float*)d_in[18];

    char* wsb = (char*)d_ws;
    float*  gnn    = (float*) (wsb + 0);           // 12,845,056 B
    double* stats  = (double*)(wsb + 12845056);    // 256 B
    float*  xfws   = (float*) (wsb + 12845312);    // 14,450,688 B
    double* invnws = (double*)(wsb + 27296000);    // 802,816 B
    float*  pval   = (float*) (wsb + 28098816);    // 14,450,688 B
    short*  pidx   = (short*) (wsb + 42549504);    // 7,225,344 B  (end ~49.8 MB)

    hipMemsetAsync(stats, 0, 32 * sizeof(double), stream);
    fconv_rstats_kernel<<<NWIN + 784, 512, 0, stream>>>(
        x_in, f_w, f_b, f_gn_w, f_gn_b, r_w, r_b, xfws, invnws, stats);
    sim_kernel<<<NWIN * 4, 256, 0, stream>>>(xfws, invnws, pval, pidx);
    merge_mlp_kernel<<<NWIN, 512, 0, stream>>>(
        xfws, pval, pidx, e1_w, e1_b, e2_w, e2_b, gamma, beta, p_w, p_b, gnn, stats);
    final_kernel<<<1568, 256, 0, stream>>>(
        x_in, gnn, r_w, r_b, r_gn_w, r_gn_b, p_w, p_b, p_gn_w, p_gn_b, stats, (float*)d_out);
}

// Round 5
// 407.988 us; speedup vs baseline: 1.5569x; 1.0592x over previous
//
#include <hip/hip_runtime.h>
#include <hip/hip_fp16.h>
#include <math.h>

#define CIN 128
#define C4  32
#define HW  12544      // 112*112
#define NPIX 256       // nodes per window
#define KNB 9
#define NWIN 392       // 8 * 7 * 7

__device__ inline double wave_sum(double v) {
#pragma unroll
    for (int off = 32; off; off >>= 1) v += __shfl_down(v, off);
    return v;
}

// predicated stable insert: strict '>' keeps earlier-inserted on ties (== lax.top_k)
#define TOP9_INSERT(sv, mi, tv, ti)                                  \
    {                                                                \
        _Pragma("unroll")                                            \
        for (int j = KNB - 1; j >= 1; --j) {                         \
            bool cj  = (sv) > tv[j];                                 \
            bool cjm = (sv) > tv[j - 1];                             \
            tv[j] = cj ? (cjm ? tv[j - 1] : (sv)) : tv[j];           \
            ti[j] = cj ? (cjm ? ti[j - 1] : (mi)) : ti[j];           \
        }                                                            \
        bool c0 = (sv) > tv[0];                                      \
        tv[0] = c0 ? (sv) : tv[0];                                   \
        ti[0] = c0 ? (mi) : ti[0];                                   \
    }

// ================= K1: fconv (blocks 0..391) + r-stats (blocks 392..1175) =================
__global__ __launch_bounds__(512, 2) void fconv_rstats_kernel(
    const float* __restrict__ x_in,
    const float* __restrict__ f_w, const float* __restrict__ f_b,
    const float* __restrict__ f_gn_w, const float* __restrict__ f_gn_b,
    const float* __restrict__ r_w, const float* __restrict__ r_b,
    float* __restrict__ xfws, double* __restrict__ invnws,
    double* __restrict__ stats)
{
    __shared__ __align__(16) char smem[34944];
    const int t = threadIdx.x;

    if (blockIdx.x < NWIN) {
        double* wbufd = (double*)smem;              // [0,32768) f_w as fp64 paired-c
        double* vbuf  = (double*)smem;              // reuse: [256][17] fp64
        double* red   = (double*)(smem + 34816);
        const int win = blockIdx.x;
        const int b = win / 49, wg = (win / 7) % 7, hg = win % 7;
        const int n = t & 255, s = t >> 8;
        const int py = n >> 4, px = n & 15;

        for (int i = t; i < C4 * CIN; i += 512) {
            int o = i >> 7, c = i & 127;
            wbufd[(c >> 1) * 64 + o * 2 + (c & 1)] = (double)f_w[i];
        }
        __syncthreads();

        const float* xb = x_in + (size_t)b * CIN * HW + (size_t)(wg * 16 + py) * 112 + (hg * 16 + px);
        double acc[16];
#pragma unroll
        for (int j = 0; j < 16; ++j) acc[j] = 0.0;
        {
            const double2* wrow = (const double2*)wbufd + 16 * s;
            for (int c2 = 0; c2 < 64; ++c2) {
                double xv0 = (double)xb[(size_t)(2 * c2) * HW];
                double xv1 = (double)xb[(size_t)(2 * c2 + 1) * HW];
                const double2* wr = wrow + c2 * 32;
#pragma unroll
                for (int j = 0; j < 16; ++j) {
                    double2 w2 = wr[j];
                    acc[j] = fma(w2.x, xv0, acc[j]);
                    acc[j] = fma(w2.y, xv1, acc[j]);
                }
            }
        }
        double s1 = 0.0, s2 = 0.0;
#pragma unroll
        for (int j = 0; j < 16; ++j) {
            double v = acc[j] + (double)f_b[16 * s + j];
            acc[j] = v; s1 += v; s2 += v * v;
        }
        s1 = wave_sum(s1); s2 = wave_sum(s2);
        {
            int w = t >> 6;
            if ((t & 63) == 0) { red[w] = s1; red[8 + w] = s2; }
        }
        __syncthreads();
        double rs1 = 0.0, rs2 = 0.0;
#pragma unroll
        for (int w = 0; w < 8; ++w) { rs1 += red[w]; rs2 += red[8 + w]; }
        const double mu   = rs1 * (1.0 / 8192.0);
        const double var  = rs2 * (1.0 / 8192.0) - mu * mu;
        const double rstd = 1.0 / sqrt(var + 1e-5);

        float myv[16];
#pragma unroll
        for (int j = 0; j < 16; ++j) {
            int c = 16 * s + j;
            myv[j] = (float)((acc[j] - mu) * rstd * (double)f_gn_w[c] + (double)f_gn_b[c]);
        }
        float* xrow = xfws + (size_t)(win * 256 + n) * 36;
#pragma unroll
        for (int q4 = 0; q4 < 4; ++q4) {
            float4 f = { myv[4 * q4], myv[4 * q4 + 1], myv[4 * q4 + 2], myv[4 * q4 + 3] };
            ((float4*)(xrow + 16 * s))[q4] = f;
        }
        const double ginv = 1.0 / (sqrt(5440.0 / 255.0) + 1e-5);
        const float gyf = (float)(((double)py - 7.5) * ginv);
        const float gxf = (float)(((double)px - 7.5) * ginv);
        if (s == 0) {
            float4 g4 = { gyf, gxf, 0.f, 0.f };
            ((float4*)(xrow + 32))[0] = g4;
        }
        if (s == 1) {
#pragma unroll
            for (int j = 0; j < 16; ++j) vbuf[n * 17 + j] = (double)myv[j];
        }
        __syncthreads();
        if (s == 0) {
            double nrm = 0.0;
#pragma unroll
            for (int j = 0; j < 16; ++j) { double x = (double)myv[j]; nrm += x * x; }
#pragma unroll
            for (int j = 0; j < 16; ++j) { double x = vbuf[n * 17 + j]; nrm += x * x; }
            double xg = (double)gyf; nrm += xg * xg;
            double xh = (double)gxf; nrm += xh * xh;
            invnws[win * 256 + n] = 1.0 / fmax(sqrt(nrm), 1e-8);
        }
    } else {
        float*  wt  = (float*)smem;                 // 32KB [c][64]
        double* red = (double*)(smem + 34816);
        const int idx = blockIdx.x - NWIN;
        const int b = idx / 98, rem = idx % 98;
        const int oc = rem / 49, pg = rem % 49;
        const int sh = t >> 8, n = t & 255;
        for (int i = t; i < 64 * CIN; i += 512)
            wt[(i & 127) * 64 + (i >> 7)] = r_w[oc * 64 * CIN + i];
        __syncthreads();
        const float* xb = x_in + (size_t)b * CIN * HW + pg * 256 + n;
        float acc[32];
#pragma unroll
        for (int o = 0; o < 32; ++o) acc[o] = r_b[oc * 64 + sh * 32 + o];
        for (int c0 = 0; c0 < CIN; c0 += 8) {
            float xv[8];
#pragma unroll
            for (int u = 0; u < 8; ++u) xv[u] = xb[(size_t)(c0 + u) * HW];
#pragma unroll
            for (int u = 0; u < 8; ++u)
#pragma unroll
                for (int o = 0; o < 32; ++o)
                    acc[o] = fmaf(wt[(c0 + u) * 64 + sh * 32 + o], xv[u], acc[o]);
        }
        double s1 = 0.0, s2 = 0.0;
#pragma unroll
        for (int o = 0; o < 32; ++o) { double v = (double)acc[o]; s1 += v; s2 += v * v; }
        s1 = wave_sum(s1); s2 = wave_sum(s2);
        {
            int w = t >> 6;
            if ((t & 63) == 0) { red[w] = s1; red[8 + w] = s2; }
        }
        __syncthreads();
        if (t == 0) {
            double a = 0.0, c = 0.0;
#pragma unroll
            for (int w = 0; w < 8; ++w) { a += red[w]; c += red[8 + w]; }
            atomicAdd(&stats[b * 4 + 0], a);
            atomicAdd(&stats[b * 4 + 1], c);
        }
    }
}

// ================= K2: sim + partial top-9, block = (window, m-quarter) =================
__global__ __launch_bounds__(256, 4) void sim_kernel(
    const float* __restrict__ xfws, const double* __restrict__ invnws,
    float* __restrict__ pval, short* __restrict__ pidx)
{
    __shared__ __align__(16) float xfm[64 * 36];
    __shared__ double invm[64];
    const int bid = blockIdx.x;
    const int win = bid >> 2, m0 = (bid & 3) << 6;
    const int n = threadIdx.x;

    const float* src = xfws + (size_t)(win * 256 + m0) * 36;
    for (int i = n; i < 64 * 36; i += 256) xfm[i] = src[i];
    if (n < 64) invm[n] = invnws[win * 256 + m0 + n];

    double xad[36];
    {
        const float4* own = (const float4*)(xfws + (size_t)(win * 256 + n) * 36);
#pragma unroll
        for (int q = 0; q < 9; ++q) {
            float4 f = own[q];
            xad[q * 4 + 0] = (double)f.x; xad[q * 4 + 1] = (double)f.y;
            xad[q * 4 + 2] = (double)f.z; xad[q * 4 + 3] = (double)f.w;
        }
    }
    const double inv_self = invnws[win * 256 + n];
    __syncthreads();

    float tv[KNB]; int ti[KNB];
#pragma unroll
    for (int k = 0; k < KNB; ++k) { tv[k] = -INFINITY; ti[k] = 0; }
#pragma unroll 2
    for (int mm = 0; mm < 64; ++mm) {
        const int m = m0 + mm;
        const float4* xm = (const float4*)(xfm + mm * 36);
        double d0 = 0.0, d1 = 0.0, d2 = 0.0, d3 = 0.0;
#pragma unroll
        for (int q = 0; q < 9; ++q) {
            float4 f = xm[q];
            d0 = fma((double)f.x, xad[q * 4 + 0], d0);
            d1 = fma((double)f.y, xad[q * 4 + 1], d1);
            d2 = fma((double)f.z, xad[q * 4 + 2], d2);
            d3 = fma((double)f.w, xad[q * 4 + 3], d3);
        }
        double d = (d0 + d1) + (d2 + d3);
        float sv = (float)(d * (inv_self * invm[mm]));
        sv = (m == n) ? -INFINITY : sv;
        TOP9_INSERT(sv, m, tv, ti);
    }
    const size_t base = ((size_t)bid * 256 + n) * 9;
#pragma unroll
    for (int k = 0; k < KNB; ++k) { pval[base + k] = tv[k]; pidx[base + k] = (short)ti[k]; }
}

// ================= K3: merge + separable edge MLP + aggregate + p-stats =================
// block = (window, node-half); 512 threads = (nl in [0,128), s in [0,4))
// LDS (80640 B, 2 blocks/CU), odd-padded rows for conflict-free column/gather reads:
//   [0,37888)      xf[256][37] f32        (overlay after agg: pwt[32][128] f32 16384)
//   [37888,55296)  hm[256][34] f16        (17 half2 per row; gcd(17,32)=1)
//   [55296,72192)  hs[128][33] f32        (overlay after edges: gnx[128][33] f32)
//   [72192,80384)  e1w[2048] f32          (overlay after hs/hm: Ti[1152] i16 @72192, Wt[1152] f32 @75520)
//   [80384,80512)  e2w[32] f32
//   [80512,80640)  red[16] f64
__global__ __launch_bounds__(512, 2) void merge_mlp_kernel(
    const float* __restrict__ xfws,
    const float* __restrict__ pval, const short* __restrict__ pidx,
    const float* __restrict__ e1_w, const float* __restrict__ e1_b,
    const float* __restrict__ e2_w, const float* __restrict__ e2_b,
    const float* __restrict__ gamma, const float* __restrict__ beta,
    const float* __restrict__ p_w, const float* __restrict__ p_b,
    float* __restrict__ gnn, double* __restrict__ stats)
{
    __shared__ __align__(16) char smem[80640];
    float*   xf    = (float*)smem;                  // [256][37]
    __half2* hm2   = (__half2*)(smem + 37888);      // [256][17]
    float*   hs    = (float*)(smem + 55296);        // [128][33]
    float*   e1w   = (float*)(smem + 72192);
    short*   Ti    = (short*)(smem + 72192);        // overlay
    float*   Wt    = (float*)(smem + 75520);        // overlay
    float*   e2w_s = (float*)(smem + 80384);
    double*  red   = (double*)(smem + 80512);
    float*   pwt   = (float*)smem;                  // overlay: [32][128]
    float*   gnx   = (float*)(smem + 55296);        // overlay: [128][33]

    const int bid  = blockIdx.x;
    const int win  = bid >> 1, half = bid & 1;
    const int b = win / 49, wg = (win / 7) % 7, hg = win % 7;
    const int t = threadIdx.x;
    const int nl = t & 127, s = t >> 7;
    const int gn = half * 128 + nl;                 // this thread's node (global in window)

    // load xf (padded rows) + e1w + e2w
    {
        const float* src = xfws + (size_t)win * 256 * 36;
        for (int i = t; i < 9216; i += 512) xf[(i / 36) * 37 + (i % 36)] = src[i];
        for (int i = t; i < 2048; i += 512) e1w[i] = e1_w[i];
        if (t < C4) e2w_s[t] = e2_w[t];
    }
    __syncthreads();

    // hs: thread (nl,s) computes hs[nl][8s..8s+8) for its own node gn
    {
        float xr[C4];
#pragma unroll
        for (int c = 0; c < C4; ++c) xr[c] = xf[gn * 37 + c];
        const int j0 = 8 * s;
#pragma unroll
        for (int jj = 0; jj < 8; ++jj) {
            const int j = j0 + jj;
            float h0 = e1_b[j], h1 = 0.f;
#pragma unroll
            for (int c = 0; c < C4; c += 2) {
                h0 = fmaf(e1w[j * 64 + c], xr[c], h0);
                h1 = fmaf(e1w[j * 64 + c + 1], xr[c + 1], h1);
            }
            hs[nl * 33 + j] = h0 + h1;
        }
    }
    // hm: thread (mh = t&255, jh = t>>8) computes hm[mh][16jh..16jh+16) (fp16)
    {
        const int mh = t & 255, jh = t >> 8;
        float xr[C4];
#pragma unroll
        for (int c = 0; c < C4; ++c) xr[c] = xf[mh * 37 + c];
        const int j0 = 16 * jh;
#pragma unroll
        for (int u = 0; u < 8; ++u) {
            const int j = j0 + 2 * u;
            float a0 = 0.f, a1 = 0.f;
#pragma unroll
            for (int c = 0; c < C4; ++c) {
                a0 = fmaf(e1w[j * 64 + 32 + c], xr[c], a0);
                a1 = fmaf(e1w[(j + 1) * 64 + 32 + c], xr[c], a1);
            }
            hm2[mh * 17 + 8 * jh + u] = __floats2half2_rn(a0, a1);
        }
    }
    __syncthreads();   // hs/hm done; e1w now dead -> Ti/Wt overlay becomes legal

    // merge 4 quarter top-9 lists (s==0 threads; ascending qd == ascending m => stable)
    if (s == 0) {
        float tv[KNB]; int ti[KNB];
#pragma unroll
        for (int k = 0; k < KNB; ++k) { tv[k] = -INFINITY; ti[k] = 0; }
        for (int qd = 0; qd < 4; ++qd) {
            const size_t base = ((size_t)(win * 4 + qd) * 256 + gn) * 9;
#pragma unroll
            for (int k = 0; k < KNB; ++k) {
                float sv = pval[base + k];
                int   mi = (int)pidx[base + k];
                TOP9_INSERT(sv, mi, tv, ti);
            }
        }
#pragma unroll
        for (int k = 0; k < KNB; ++k) Ti[nl * 9 + k] = (short)ti[k];
    }
    __syncthreads();

    // edges: wgt = sigmoid(e2 . silu(hs[n] + hm[m]) + e2b); k in {s, s+4, s+8}
    {
        float hsr[C4];
#pragma unroll
        for (int c = 0; c < C4; ++c) hsr[c] = hs[nl * 33 + c];
        const float e2b = e2_b[0];
        for (int k = s; k < KNB; k += 4) {
            const int m = (int)Ti[nl * 9 + k];
            float a2 = 0.f;
#pragma unroll
            for (int jp = 0; jp < 16; ++jp) {
                float2 hv = __half22float2(hm2[m * 17 + jp]);
                float h0 = hsr[2 * jp] + hv.x;
                float h1 = hsr[2 * jp + 1] + hv.y;
                float sg0 = 1.f / (1.f + __expf(-h0));
                a2 = fmaf(e2w_s[2 * jp], h0 * sg0, a2);
                float sg1 = 1.f / (1.f + __expf(-h1));
                a2 = fmaf(e2w_s[2 * jp + 1], h1 * sg1, a2);
            }
            Wt[nl * 9 + k] = 1.f / (1.f + __expf(-(a2 + e2b)));
        }
    }
    __syncthreads();

    // aggregate: thread (nl,s) handles channels [8s,8s+8); write gnn + gnx
    {
        short tis[KNB]; float wks[KNB];
#pragma unroll
        for (int k = 0; k < KNB; ++k) { tis[k] = Ti[nl * 9 + k]; wks[k] = Wt[nl * 9 + k]; }
        const float g = gamma[0], be = beta[0];
        const int py = gn >> 4, px = gn & 15;
        float* gp = gnn + (size_t)b * C4 * HW + (size_t)(wg * 16 + py) * 112 + (hg * 16 + px);
        const int c0 = 8 * s;
#pragma unroll
        for (int cc = 0; cc < 8; ++cc) {
            const int c = c0 + cc;
            float o = 0.f;
#pragma unroll
            for (int k = 0; k < KNB; ++k)
                o = fmaf(wks[k], xf[(int)tis[k] * 37 + c], o);
            float gl = fmaf(g, o, be * xf[gn * 37 + c]);
            gp[(size_t)c * HW] = gl;
            gnx[nl * 33 + c] = gl;
        }
    }
    __syncthreads();   // xf reads done -> pwt overlay legal; gnx complete

    // p-stats: thread (nl,s) computes p-conv outs [32s,32s+32) for node nl
    for (int i = t; i < 4096; i += 512) pwt[(i & 31) * 128 + (i >> 5)] = p_w[i];
    __syncthreads();
    {
        float gr[C4];
#pragma unroll
        for (int c = 0; c < C4; ++c) gr[c] = gnx[nl * 33 + c];
        const int o0 = 32 * s;
        double s1 = 0.0, s2 = 0.0;
        for (int o = 0; o < 32; ++o) {
            float a = p_b[o0 + o];
#pragma unroll
            for (int c = 0; c < C4; ++c) a = fmaf(pwt[c * 128 + o0 + o], gr[c], a);
            s1 += (double)a; s2 += (double)a * (double)a;
        }
        s1 = wave_sum(s1); s2 = wave_sum(s2);
        int w = t >> 6;
        if ((t & 63) == 0) { red[w] = s1; red[8 + w] = s2; }
    }
    __syncthreads();
    if (t == 0) {
        double a = 0.0, c = 0.0;
#pragma unroll
        for (int w = 0; w < 8; ++w) { a += red[w]; c += red[8 + w]; }
        atomicAdd(&stats[b * 4 + 2], a);
        atomicAdd(&stats[b * 4 + 3], c);
    }
}

// ================= final: GN(r)+GN(p)+add, block = (b, 32-out chunk, pixel group) =================
__global__ __launch_bounds__(256, 4) void final_kernel(
    const float* __restrict__ x_in, const float* __restrict__ gnn,
    const float* __restrict__ r_w, const float* __restrict__ r_b,
    const float* __restrict__ r_gn_w, const float* __restrict__ r_gn_b,
    const float* __restrict__ p_w, const float* __restrict__ p_b,
    const float* __restrict__ p_gn_w, const float* __restrict__ p_gn_b,
    const double* __restrict__ stats,
    float* __restrict__ out)
{
    __shared__ float rwt[32 * CIN];   // 16KB [c][32]
    __shared__ float pwt[32 * C4];    // 4KB  [c][32]
    const int idx = blockIdx.x;
    const int b = idx / 196, rem = idx % 196;
    const int ocq = rem / 49, pg = rem % 49;
    const int t = threadIdx.x;

    for (int i = t; i < 32 * CIN; i += 256)
        rwt[(i & 127) * 32 + (i >> 7)] = r_w[(size_t)(ocq * 32) * CIN + i];
    for (int i = t; i < 32 * C4; i += 256)
        pwt[(i & 31) * 32 + (i >> 5)] = p_w[(size_t)(ocq * 32) * C4 + i];
    __syncthreads();

    const double NN = (double)CIN * HW;
    const double mu_r = stats[b * 4 + 0] / NN;
    const float  rs_r = (float)(1.0 / sqrt(stats[b * 4 + 1] / NN - mu_r * mu_r + 1e-5));
    const double mu_p = stats[b * 4 + 2] / NN;
    const float  rs_p = (float)(1.0 / sqrt(stats[b * 4 + 3] / NN - mu_p * mu_p + 1e-5));
    const float fmur = (float)mu_r, fmup = (float)mu_p;

    const int p = pg * 256 + t;
    const float* xb = x_in + (size_t)b * CIN * HW + p;
    const float* gb = gnn + (size_t)b * C4 * HW + p;
    float* ob = out + (size_t)b * CIN * HW + p;

    float xg[C4];
#pragma unroll
    for (int c = 0; c < C4; ++c) xg[c] = gb[(size_t)c * HW];

    float accR[32], accP[32];
#pragma unroll
    for (int o = 0; o < 32; ++o) {
        accR[o] = r_b[ocq * 32 + o];
        accP[o] = p_b[ocq * 32 + o];
    }
    for (int c0 = 0; c0 < CIN; c0 += 8) {
        float xv[8];
#pragma unroll
        for (int u = 0; u < 8; ++u) xv[u] = xb[(size_t)(c0 + u) * HW];
#pragma unroll
        for (int u = 0; u < 8; ++u)
#pragma unroll
            for (int o = 0; o < 32; ++o)
                accR[o] = fmaf(rwt[(c0 + u) * 32 + o], xv[u], accR[o]);
    }
#pragma unroll
    for (int c = 0; c < C4; ++c)
#pragma unroll
        for (int o = 0; o < 32; ++o)
            accP[o] = fmaf(pwt[c * 32 + o], xg[c], accP[o]);

#pragma unroll
    for (int o = 0; o < 32; ++o) {
        const int O = ocq * 32 + o;
        float yr = (accR[o] - fmur) * rs_r * r_gn_w[O] + r_gn_b[O];
        float yp = (accP[o] - fmup) * rs_p * p_gn_w[O] + p_gn_b[O];
        ob[(size_t)O * HW] = yp + yr;
    }
}

extern "C" void kernel_launch(void* const* d_in, const int* in_sizes, int n_in,
                              void* d_out, int out_size, void* d_ws, size_t ws_size,
                              hipStream_t stream)
{
    const float* x_in   = (const float*)d_in[0];
    const float* f_w    = (const float*)d_in[1];
    const float* f_b    = (const float*)d_in[2];
    const float* f_gn_w = (const float*)d_in[3];
    const float* f_gn_b = (const float*)d_in[4];
    const float* p_w    = (const float*)d_in[5];
    const float* p_b    = (const float*)d_in[6];
    const float* p_gn_w = (const float*)d_in[7];
    const float* p_gn_b = (const float*)d_in[8];
    const float* r_w    = (const float*)d_in[9];
    const float* r_b    = (const float*)d_in[10];
    const float* r_gn_w = (const float*)d_in[11];
    const float* r_gn_b = (const float*)d_in[12];
    const float* e1_w   = (const float*)d_in[13];
    const float* e1_b   = (const float*)d_in[14];
    const float* e2_w   = (const float*)d_in[15];
    const float* e2_b   = (const float*)d_in[16];
    const float* gamma  = (const float*)d_in[17];
    const float* beta   = (const float*)d_in[18];

    char* wsb = (char*)d_ws;
    float*  gnn    = (float*) (wsb + 0);           // 12,845,056 B
    double* stats  = (double*)(wsb + 12845056);    // 256 B
    float*  xfws   = (float*) (wsb + 12845312);    // 14,450,688 B
    double* invnws = (double*)(wsb + 27296000);    // 802,816 B
    float*  pval   = (float*) (wsb + 28098816);    // 14,450,688 B
    short*  pidx   = (short*) (wsb + 42549504);    // 7,225,344 B

    hipMemsetAsync(stats, 0, 32 * sizeof(double), stream);
    fconv_rstats_kernel<<<NWIN + 784, 512, 0, stream>>>(
        x_in, f_w, f_b, f_gn_w, f_gn_b, r_w, r_b, xfws, invnws, stats);
    sim_kernel<<<NWIN * 4, 256, 0, stream>>>(xfws, invnws, pval, pidx);
    merge_mlp_kernel<<<NWIN * 2, 512, 0, stream>>>(
        xfws, pval, pidx, e1_w, e1_b, e2_w, e2_b, gamma, beta, p_w, p_b, gnn, stats);
    final_kernel<<<1568, 256, 0, stream>>>(
        x_in, gnn, r_w, r_b, r_gn_w, r_gn_b, p_w, p_b, p_gn_w, p_gn_b, stats, (float*)d_out);
}

// Round 6
// 327.115 us; speedup vs baseline: 1.9418x; 1.2472x over previous
//
#include <hip/hip_runtime.h>
#include <hip/hip_fp16.h>
#include <math.h>

#define CIN 128
#define C4  32
#define HW  12544      // 112*112
#define KNB 9
#define NWIN 392       // 8 * 7 * 7

__device__ inline double wave_sum(double v) {
#pragma unroll
    for (int off = 32; off; off >>= 1) v += __shfl_down(v, off);
    return v;
}

// predicated stable insert: strict '>' keeps earlier-inserted on ties (== lax.top_k)
#define TOP9_INSERT(sv, mi, tv, ti)                                  \
    {                                                                \
        _Pragma("unroll")                                            \
        for (int j = KNB - 1; j >= 1; --j) {                         \
            bool cj  = (sv) > tv[j];                                 \
            bool cjm = (sv) > tv[j - 1];                             \
            tv[j] = cj ? (cjm ? tv[j - 1] : (sv)) : tv[j];           \
            ti[j] = cj ? (cjm ? ti[j - 1] : (mi)) : ti[j];           \
        }                                                            \
        bool c0 = (sv) > tv[0];                                      \
        tv[0] = c0 ? (sv) : tv[0];                                   \
        ti[0] = c0 ? (mi) : ti[0];                                   \
    }

// ================= prep: weight transposes for scalar-load-friendly layouts =================
__global__ __launch_bounds__(256) void prep_kernel(
    const float* __restrict__ f_w, const float* __restrict__ r_w,
    const float* __restrict__ p_w,
    double* __restrict__ fw64t, float* __restrict__ rwt_t, float* __restrict__ pwt_t)
{
    const int i = blockIdx.x * 256 + threadIdx.x;
    if (i < 4096)  fw64t[(i & 127) * 32 + (i >> 7)]  = (double)f_w[i];  // [c][o], o<32
    if (i < 16384) rwt_t[(i & 127) * 128 + (i >> 7)] = r_w[i];          // [c][o], o<128
    if (i < 4096)  pwt_t[(i & 31) * 128 + (i >> 5)]  = p_w[i];          // [c][o], c<32
}

// ================= K1: fconv (blocks 0..391) + r-stats (blocks 392..1175) =================
__global__ __launch_bounds__(512, 2) void fconv_rstats_kernel(
    const float* __restrict__ x_in,
    const double* __restrict__ fw64t, const float* __restrict__ f_b,
    const float* __restrict__ f_gn_w, const float* __restrict__ f_gn_b,
    const float* __restrict__ rwt_t, const float* __restrict__ r_b,
    float* __restrict__ xfws, double* __restrict__ invnws,
    double* __restrict__ stats)
{
    __shared__ __align__(16) char smem[34944];
    double* vbuf = (double*)smem;               // [256][17] f64 exchange
    double* red  = (double*)(smem + 34816);     // [16]
    const int t = threadIdx.x;

    if (blockIdx.x < NWIN) {
        const int win = blockIdx.x;
        const int b = win / 49, wg = (win / 7) % 7, hg = win % 7;
        const int n = t & 255, s = t >> 8;
        const int py = n >> 4, px = n & 15;
        const int rs = __builtin_amdgcn_readfirstlane(s);

        const float* xb = x_in + (size_t)b * CIN * HW + (size_t)(wg * 16 + py) * 112 + (hg * 16 + px);
        const double* wB = fw64t + 16 * rs;     // wave-uniform base -> s_load weights
        double acc[16];
#pragma unroll
        for (int j = 0; j < 16; ++j) acc[j] = 0.0;
#pragma unroll 2
        for (int c = 0; c < CIN; ++c) {
            double xv = (double)xb[(size_t)c * HW];
            const double* wr = wB + c * 32;
#pragma unroll
            for (int j = 0; j < 16; ++j) acc[j] = fma(wr[j], xv, acc[j]);
        }
        double s1 = 0.0, s2 = 0.0;
#pragma unroll
        for (int j = 0; j < 16; ++j) {
            double v = acc[j] + (double)f_b[16 * rs + j];
            acc[j] = v; s1 += v; s2 += v * v;
        }
        s1 = wave_sum(s1); s2 = wave_sum(s2);
        {
            int w = t >> 6;
            if ((t & 63) == 0) { red[w] = s1; red[8 + w] = s2; }
        }
        __syncthreads();
        double rs1 = 0.0, rs2 = 0.0;
#pragma unroll
        for (int w = 0; w < 8; ++w) { rs1 += red[w]; rs2 += red[8 + w]; }
        const double mu   = rs1 * (1.0 / 8192.0);
        const double var  = rs2 * (1.0 / 8192.0) - mu * mu;
        const double rstd = 1.0 / sqrt(var + 1e-5);

        float myv[16];
#pragma unroll
        for (int j = 0; j < 16; ++j) {
            int c = 16 * rs + j;
            myv[j] = (float)((acc[j] - mu) * rstd * (double)f_gn_w[c] + (double)f_gn_b[c]);
        }
        float* xrow = xfws + (size_t)(win * 256 + n) * 36;
#pragma unroll
        for (int q4 = 0; q4 < 4; ++q4) {
            float4 f = { myv[4 * q4], myv[4 * q4 + 1], myv[4 * q4 + 2], myv[4 * q4 + 3] };
            ((float4*)(xrow + 16 * rs))[q4] = f;
        }
        const double ginv = 1.0 / (sqrt(5440.0 / 255.0) + 1e-5);   // 1/(grid std ddof=1 + eps)
        const float gyf = (float)(((double)py - 7.5) * ginv);
        const float gxf = (float)(((double)px - 7.5) * ginv);
        if (s == 0) {
            float4 g4 = { gyf, gxf, 0.f, 0.f };
            ((float4*)(xrow + 32))[0] = g4;
        }
        if (s == 1) {
#pragma unroll
            for (int j = 0; j < 16; ++j) vbuf[n * 17 + j] = (double)myv[j];
        }
        __syncthreads();
        if (s == 0) {
            double nrm = 0.0;
#pragma unroll
            for (int j = 0; j < 16; ++j) { double x = (double)myv[j]; nrm += x * x; }
#pragma unroll
            for (int j = 0; j < 16; ++j) { double x = vbuf[n * 17 + j]; nrm += x * x; }
            double xg = (double)gyf; nrm += xg * xg;
            double xh = (double)gxf; nrm += xh * xh;
            invnws[win * 256 + n] = 1.0 / fmax(sqrt(nrm), 1e-8);
        }
    } else {
        const int idx = blockIdx.x - NWIN;
        const int b = idx / 98, rem = idx % 98;
        const int oc = rem / 49, pg = rem % 49;
        const int sh = t >> 8, n = t & 255;
        const int rsh = __builtin_amdgcn_readfirstlane(sh);
        const float* wR = rwt_t + oc * 64 + rsh * 32;   // + c*128 per step, s_load
        const float* xb = x_in + (size_t)b * CIN * HW + pg * 256 + n;
        float acc[32];
#pragma unroll
        for (int o = 0; o < 32; ++o) acc[o] = r_b[oc * 64 + rsh * 32 + o];
#pragma unroll 2
        for (int c = 0; c < CIN; ++c) {
            float xv = xb[(size_t)c * HW];
            const float* wr = wR + c * 128;
#pragma unroll
            for (int o = 0; o < 32; ++o) acc[o] = fmaf(wr[o], xv, acc[o]);
        }
        double s1 = 0.0, s2 = 0.0;
#pragma unroll
        for (int o = 0; o < 32; ++o) { double v = (double)acc[o]; s1 += v; s2 += v * v; }
        s1 = wave_sum(s1); s2 = wave_sum(s2);
        {
            int w = t >> 6;
            if ((t & 63) == 0) { red[w] = s1; red[8 + w] = s2; }
        }
        __syncthreads();
        if (t == 0) {
            double a = 0.0, c = 0.0;
#pragma unroll
            for (int w = 0; w < 8; ++w) { a += red[w]; c += red[8 + w]; }
            atomicAdd(&stats[b * 4 + 0], a);
            atomicAdd(&stats[b * 4 + 1], c);
        }
    }
}

// ================= K2: sim + partial top-9; zero LDS, xm rows via scalar loads =================
__global__ __launch_bounds__(256, 4) void sim_kernel(
    const float* __restrict__ xfws, const double* __restrict__ invnws,
    float* __restrict__ pval, short* __restrict__ pidx)
{
    const int bid = blockIdx.x;
    const int win = bid >> 2, m0 = (bid & 3) << 6;
    const int n = threadIdx.x;

    double xad[34];
    {
        const float4* own = (const float4*)(xfws + (size_t)(win * 256 + n) * 36);
#pragma unroll
        for (int q = 0; q < 8; ++q) {
            float4 f = own[q];
            xad[q * 4 + 0] = (double)f.x; xad[q * 4 + 1] = (double)f.y;
            xad[q * 4 + 2] = (double)f.z; xad[q * 4 + 3] = (double)f.w;
        }
        float4 g = own[8];
        xad[32] = (double)g.x; xad[33] = (double)g.y;
    }
    const double inv_self = invnws[(size_t)win * 256 + n];
    const float*  xmb  = xfws + (size_t)(win * 256 + m0) * 36;   // block-uniform rows
    const double* invb = invnws + (size_t)win * 256 + m0;

    float tv[KNB]; int ti[KNB];
#pragma unroll
    for (int k = 0; k < KNB; ++k) { tv[k] = -INFINITY; ti[k] = 0; }
#pragma unroll 2
    for (int mm = 0; mm < 64; ++mm) {
        const float* xm = xmb + mm * 36;     // uniform -> s_load batches
        double d0 = 0.0, d1 = 0.0, d2 = 0.0, d3 = 0.0;
#pragma unroll
        for (int q = 0; q < 8; ++q) {
            d0 = fma((double)xm[4 * q + 0], xad[4 * q + 0], d0);
            d1 = fma((double)xm[4 * q + 1], xad[4 * q + 1], d1);
            d2 = fma((double)xm[4 * q + 2], xad[4 * q + 2], d2);
            d3 = fma((double)xm[4 * q + 3], xad[4 * q + 3], d3);
        }
        d0 = fma((double)xm[32], xad[32], d0);
        d1 = fma((double)xm[33], xad[33], d1);
        double d = (d0 + d1) + (d2 + d3);
        float sv = (float)(d * (inv_self * invb[mm]));
        sv = (m0 + mm == n) ? -INFINITY : sv;
        TOP9_INSERT(sv, m0 + mm, tv, ti);
    }
    const size_t base = ((size_t)bid * 256 + n) * 9;
#pragma unroll
    for (int k = 0; k < KNB; ++k) { pval[base + k] = tv[k]; pidx[base + k] = (short)ti[k]; }
}

// ================= K3: merge + separable MLP + aggregate + p-stats; weights via scalar =================
// block = (window, node-half); 512 threads = (nl in [0,128), s in [0,4))
// LDS 75136 B (2 blocks/CU):
//   [0,33792)      xf[256][33] f32 (32 feats + pad col)
//   [33792,51200)  hm[256][17] half2
//   [51200,68096)  hs[128][33] f32   (overlay after edges: gnx[128][33])
//   [68096,70400)  Ti[1152] i16
//   [70400,75008)  Wt[1152] f32
//   [75008,75136)  red[16] f64
__global__ __launch_bounds__(512, 2) void merge_mlp_kernel(
    const float* __restrict__ xfws,
    const float* __restrict__ pval, const short* __restrict__ pidx,
    const float* __restrict__ e1_w, const float* __restrict__ e1_b,
    const float* __restrict__ e2_w, const float* __restrict__ e2_b,
    const float* __restrict__ gamma, const float* __restrict__ beta,
    const float* __restrict__ pwt_t, const float* __restrict__ p_b,
    float* __restrict__ gnn, double* __restrict__ stats)
{
    __shared__ __align__(16) char smem[75136];
    float*   xf  = (float*)smem;
    __half2* hm2 = (__half2*)(smem + 33792);
    float*   hs  = (float*)(smem + 51200);
    float*   gnx = (float*)(smem + 51200);      // overlay after edges
    short*   Ti  = (short*)(smem + 68096);
    float*   Wt  = (float*)(smem + 70400);
    double*  red = (double*)(smem + 75008);

    const int bid = blockIdx.x;
    const int win = bid >> 1, half = bid & 1;
    const int b = win / 49, wg = (win / 7) % 7, hg = win % 7;
    const int t = threadIdx.x;
    const int nl = t & 127, s = t >> 7;
    const int gn = half * 128 + nl;
    const int rs = __builtin_amdgcn_readfirstlane(s);

    // stage xf: 32 feature cols, stride 33 (conflict-free per-lane rows)
    {
        const float* src = xfws + (size_t)win * 256 * 36;
        for (int i = t; i < 8192; i += 512)
            xf[(i >> 5) * 33 + (i & 31)] = src[(i >> 5) * 36 + (i & 31)];
    }
    __syncthreads();

    // hs: thread (nl,s) computes hs[nl][8rs..8rs+8) for own node gn; e1 weights via s_load
    {
        float xr[C4];
#pragma unroll
        for (int c = 0; c < C4; ++c) xr[c] = xf[gn * 33 + c];
#pragma unroll
        for (int jj = 0; jj < 8; ++jj) {
            const int j = 8 * rs + jj;
            const float* w = e1_w + j * 64;
            float h0 = e1_b[j], h1 = 0.f;
#pragma unroll
            for (int c = 0; c < C4; c += 2) {
                h0 = fmaf(w[c], xr[c], h0);
                h1 = fmaf(w[c + 1], xr[c + 1], h1);
            }
            hs[nl * 33 + j] = h0 + h1;
        }
    }
    // hm: thread (mh = t&255, jh = t>>8) computes hm[mh][16jh..16jh+16) in fp16
    {
        const int mh = t & 255;
        const int rjh = __builtin_amdgcn_readfirstlane(t >> 8);
        float xr[C4];
#pragma unroll
        for (int c = 0; c < C4; ++c) xr[c] = xf[mh * 33 + c];
#pragma unroll
        for (int u = 0; u < 8; ++u) {
            const int j = 16 * rjh + 2 * u;
            const float* w0 = e1_w + j * 64 + 32;
            const float* w1 = e1_w + (j + 1) * 64 + 32;
            float a0 = 0.f, a1 = 0.f;
#pragma unroll
            for (int c = 0; c < C4; ++c) {
                a0 = fmaf(w0[c], xr[c], a0);
                a1 = fmaf(w1[c], xr[c], a1);
            }
            hm2[mh * 17 + 8 * rjh + u] = __floats2half2_rn(a0, a1);
        }
    }
    // merge 4 quarter top-9 lists (s==0 threads; ascending qd == ascending m => stable)
    if (s == 0) {
        float tv[KNB]; int ti[KNB];
#pragma unroll
        for (int k = 0; k < KNB; ++k) { tv[k] = -INFINITY; ti[k] = 0; }
        for (int qd = 0; qd < 4; ++qd) {
            const size_t base = ((size_t)(win * 4 + qd) * 256 + gn) * 9;
#pragma unroll
            for (int k = 0; k < KNB; ++k) {
                float sv = pval[base + k];
                int   mi = (int)pidx[base + k];
                TOP9_INSERT(sv, mi, tv, ti);
            }
        }
#pragma unroll
        for (int k = 0; k < KNB; ++k) Ti[nl * 9 + k] = (short)ti[k];
    }
    __syncthreads();

    // edges: wgt = sigmoid(e2 . silu(hs[n] + hm[m]) + e2b); k in {s, s+4, s+8}
    {
        float hsr[C4];
#pragma unroll
        for (int c = 0; c < C4; ++c) hsr[c] = hs[nl * 33 + c];
        const float e2b = e2_b[0];
        for (int k = s; k < KNB; k += 4) {
            const int m = (int)Ti[nl * 9 + k];
            float a2 = 0.f;
#pragma unroll
            for (int jp = 0; jp < 16; ++jp) {
                float2 hv = __half22float2(hm2[m * 17 + jp]);
                float h0 = hsr[2 * jp] + hv.x;
                float h1 = hsr[2 * jp + 1] + hv.y;
                float sg0 = 1.f / (1.f + __expf(-h0));
                a2 = fmaf(e2_w[2 * jp], h0 * sg0, a2);
                float sg1 = 1.f / (1.f + __expf(-h1));
                a2 = fmaf(e2_w[2 * jp + 1], h1 * sg1, a2);
            }
            Wt[nl * 9 + k] = 1.f / (1.f + __expf(-(a2 + e2b)));
        }
    }
    __syncthreads();

    // aggregate: thread (nl,s) channels [8rs,8rs+8); write gnn + gnx (overlay hs)
    {
        short tis[KNB]; float wks[KNB];
#pragma unroll
        for (int k = 0; k < KNB; ++k) { tis[k] = Ti[nl * 9 + k]; wks[k] = Wt[nl * 9 + k]; }
        const float g = gamma[0], be = beta[0];
        const int py = gn >> 4, px = gn & 15;
        float* gp = gnn + (size_t)b * C4 * HW + (size_t)(wg * 16 + py) * 112 + (hg * 16 + px);
#pragma unroll
        for (int cc = 0; cc < 8; ++cc) {
            const int c = 8 * rs + cc;
            float o = 0.f;
#pragma unroll
            for (int k = 0; k < KNB; ++k)
                o = fmaf(wks[k], xf[(int)tis[k] * 33 + c], o);
            float gl = fmaf(g, o, be * xf[gn * 33 + c]);
            gp[(size_t)c * HW] = gl;
            gnx[nl * 33 + c] = gl;
        }
    }
    __syncthreads();

    // p-stats: thread (nl,s) outputs [32rs,32rs+32); weights via s_load (pwt_t [c][o])
    {
        float gr[C4];
#pragma unroll
        for (int c = 0; c < C4; ++c) gr[c] = gnx[nl * 33 + c];
        const int o0 = 32 * rs;
        float a[32];
#pragma unroll
        for (int o = 0; o < 32; ++o) a[o] = p_b[o0 + o];
#pragma unroll 2
        for (int c = 0; c < C4; ++c) {
            const float* w = pwt_t + c * 128 + o0;
#pragma unroll
            for (int o = 0; o < 32; ++o) a[o] = fmaf(w[o], gr[c], a[o]);
        }
        double s1 = 0.0, s2 = 0.0;
#pragma unroll
        for (int o = 0; o < 32; ++o) { double v = (double)a[o]; s1 += v; s2 += v * v; }
        s1 = wave_sum(s1); s2 = wave_sum(s2);
        int w = t >> 6;
        if ((t & 63) == 0) { red[w] = s1; red[8 + w] = s2; }
    }
    __syncthreads();
    if (t == 0) {
        double a = 0.0, c = 0.0;
#pragma unroll
        for (int w = 0; w < 8; ++w) { a += red[w]; c += red[8 + w]; }
        atomicAdd(&stats[b * 4 + 2], a);
        atomicAdd(&stats[b * 4 + 3], c);
    }
}

// ================= final: GN(r)+GN(p)+add; zero LDS, weights via scalar =================
__global__ __launch_bounds__(256) void final_kernel(
    const float* __restrict__ x_in, const float* __restrict__ gnn,
    const float* __restrict__ rwt_t, const float* __restrict__ r_b,
    const float* __restrict__ r_gn_w, const float* __restrict__ r_gn_b,
    const float* __restrict__ pwt_t, const float* __restrict__ p_b,
    const float* __restrict__ p_gn_w, const float* __restrict__ p_gn_b,
    const double* __restrict__ stats,
    float* __restrict__ out)
{
    const int idx = blockIdx.x;
    const int b = idx / 196, rem = idx % 196;
    const int ocq = rem / 49, pg = rem % 49;
    const int t = threadIdx.x;

    const double NN = (double)CIN * HW;
    const double mu_r = stats[b * 4 + 0] / NN;
    const float  rs_r = (float)(1.0 / sqrt(stats[b * 4 + 1] / NN - mu_r * mu_r + 1e-5));
    const double mu_p = stats[b * 4 + 2] / NN;
    const float  rs_p = (float)(1.0 / sqrt(stats[b * 4 + 3] / NN - mu_p * mu_p + 1e-5));
    const float fmur = (float)mu_r, fmup = (float)mu_p;

    const int p = pg * 256 + t;
    const float* xb = x_in + (size_t)b * CIN * HW + p;
    const float* gb = gnn + (size_t)b * C4 * HW + p;
    float* ob = out + (size_t)b * CIN * HW + p;

    float xg[C4];
#pragma unroll
    for (int c = 0; c < C4; ++c) xg[c] = gb[(size_t)c * HW];

    float accR[32], accP[32];
#pragma unroll
    for (int o = 0; o < 32; ++o) {
        accR[o] = r_b[ocq * 32 + o];
        accP[o] = p_b[ocq * 32 + o];
    }
#pragma unroll 2
    for (int c = 0; c < CIN; ++c) {
        float xv = xb[(size_t)c * HW];
        const float* w = rwt_t + c * 128 + ocq * 32;
#pragma unroll
        for (int o = 0; o < 32; ++o) accR[o] = fmaf(w[o], xv, accR[o]);
    }
#pragma unroll
    for (int c = 0; c < C4; ++c) {
        const float* w = pwt_t + c * 128 + ocq * 32;
#pragma unroll
        for (int o = 0; o < 32; ++o) accP[o] = fmaf(w[o], xg[c], accP[o]);
    }
#pragma unroll
    for (int o = 0; o < 32; ++o) {
        const int O = ocq * 32 + o;
        float yr = (accR[o] - fmur) * rs_r * r_gn_w[O] + r_gn_b[O];
        float yp = (accP[o] - fmup) * rs_p * p_gn_w[O] + p_gn_b[O];
        ob[(size_t)O * HW] = yp + yr;
    }
}

extern "C" void kernel_launch(void* const* d_in, const int* in_sizes, int n_in,
                              void* d_out, int out_size, void* d_ws, size_t ws_size,
                              hipStream_t stream)
{
    const float* x_in   = (const float*)d_in[0];
    const float* f_w    = (const float*)d_in[1];
    const float* f_b    = (const float*)d_in[2];
    const float* f_gn_w = (const float*)d_in[3];
    const float* f_gn_b = (const float*)d_in[4];
    const float* p_w    = (const float*)d_in[5];
    const float* p_b    = (const float*)d_in[6];
    const float* p_gn_w = (const float*)d_in[7];
    const float* p_gn_b = (const float*)d_in[8];
    const float* r_w    = (const float*)d_in[9];
    const float* r_b    = (const float*)d_in[10];
    const float* r_gn_w = (const float*)d_in[11];
    const float* r_gn_b = (const float*)d_in[12];
    const float* e1_w   = (const float*)d_in[13];
    const float* e1_b   = (const float*)d_in[14];
    const float* e2_w   = (const float*)d_in[15];
    const float* e2_b   = (const float*)d_in[16];
    const float* gamma  = (const float*)d_in[17];
    const float* beta   = (const float*)d_in[18];

    char* wsb = (char*)d_ws;
    float*  gnn    = (float*) (wsb + 0);           // 12,845,056
    double* stats  = (double*)(wsb + 12845056);    // 256
    float*  xfws   = (float*) (wsb + 12845312);    // 14,450,688 (f32, stride 36)
    double* invnws = (double*)(wsb + 27296000);    // 802,816
    float*  pval   = (float*) (wsb + 28098816);    // 14,450,688
    short*  pidx   = (short*) (wsb + 42549504);    // 7,225,344
    double* fw64t  = (double*)(wsb + 49774848);    // 32,768
    float*  rwt_t  = (float*) (wsb + 49807616);    // 65,536
    float*  pwt_t  = (float*) (wsb + 49873152);    // 16,384  (end ~49.9 MB)

    hipMemsetAsync(stats, 0, 32 * sizeof(double), stream);
    prep_kernel<<<64, 256, 0, stream>>>(f_w, r_w, p_w, fw64t, rwt_t, pwt_t);
    fconv_rstats_kernel<<<NWIN + 784, 512, 0, stream>>>(
        x_in, fw64t, f_b, f_gn_w, f_gn_b, rwt_t, r_b, xfws, invnws, stats);
    sim_kernel<<<NWIN * 4, 256, 0, stream>>>(xfws, invnws, pval, pidx);
    merge_mlp_kernel<<<NWIN * 2, 512, 0, stream>>>(
        xfws, pval, pidx, e1_w, e1_b, e2_w, e2_b, gamma, beta, pwt_t, p_b, gnn, stats);
    final_kernel<<<1568, 256, 0, stream>>>(
        x_in, gnn, rwt_t, r_b, r_gn_w, r_gn_b, pwt_t, p_b, p_gn_w, p_gn_b, stats, (float*)d_out);
}